// Round 11
// baseline (324.733 us; speedup 1.0000x reference)
//
#include <hip/hip_runtime.h>
#include <cstdint>

typedef unsigned short u16;
typedef __bf16 bf16x8 __attribute__((ext_vector_type(8)));
typedef float f32x4 __attribute__((ext_vector_type(4)));
typedef u16 u16x8 __attribute__((ext_vector_type(8)));

#define B_DIM 32
#define S_DIM 2048
#define D_DIM 1024
#define U_DIM 1024
#define M_TOT (B_DIM * S_DIM)   // 65536 rows

// ---------- helpers ----------
__device__ __forceinline__ u16 f2bf(float f) {
    union { float f; uint32_t u; } a; a.f = f;
    uint32_t u = a.u;
    uint32_t r = (u + 0x7FFFu + ((u >> 16) & 1u)) >> 16;   // RNE
    return (u16)r;
}
__device__ __forceinline__ float bf2f(u16 h) {
    union { uint32_t u; float f; } a; a.u = ((uint32_t)h) << 16;
    return a.f;
}
__device__ __forceinline__ float fast_tanh(float x) {
    float ax = fabsf(x);
    float e  = __expf(-2.0f * ax);
    float th = __fdividef(1.0f - e, 1.0f + e);
    return copysignf(th, x);
}
// global -> LDS async copy, 16B per lane
__device__ __forceinline__ void gload_lds16(const void* g, void* l) {
    __builtin_amdgcn_global_load_lds(
        (__attribute__((address_space(1))) void*)(uintptr_t)g,
        (__attribute__((address_space(3))) void*)(uint32_t)(uintptr_t)l,
        16, 0, 0);
}

// ---------- kernel 0: per-batch compaction of unmasked rows ----------
__global__ void build_index_kernel(const int* __restrict__ mask, int* __restrict__ idx,
                                   int* __restrict__ cnt) {
    const int b = blockIdx.x, t = threadIdx.x;
    __shared__ int wsum[4];
    const int base = t * 8;
    int m[8]; int c = 0;
#pragma unroll
    for (int i = 0; i < 8; ++i) { m[i] = mask[b * S_DIM + base + i] != 0; c += m[i]; }
    const int lane = t & 63, w = t >> 6;
    int pre = c;
    for (int o = 1; o < 64; o <<= 1) { int v = __shfl_up(pre, o); if (lane >= o) pre += v; }
    if (lane == 63) wsum[w] = pre;
    __syncthreads();
    int woff = 0;
    for (int i = 0; i < w; ++i) woff += wsum[i];
    int excl = woff + pre - c;
#pragma unroll
    for (int i = 0; i < 8; ++i) if (m[i]) idx[b * S_DIM + excl++] = base + i;
    if (t == 255) cnt[b] = woff + pre;
}

// ---------- kernel 1a: values f32 -> bf16, UNMASKED rows only ----------
__global__ void convert_masked_kernel(const float* __restrict__ values, u16* __restrict__ vbf,
                                      const int* __restrict__ idx, const int* __restrict__ cnt) {
    const int b = blockIdx.x, c = blockIdx.y, t = threadIdx.x;
    const int cb = cnt[b];
    const int i0 = c * 256;
    const int lim = (cb - i0) < 256 ? (cb - i0) : 256;
    const int* ib = idx + b * S_DIM;
    for (int ii = 0; ii < lim; ++ii) {
        const int s = ib[i0 + ii];
        const float4* src = (const float4*)(values + ((size_t)b * S_DIM + s) * D_DIM) + t;
        ushort4* dst = (ushort4*)(vbf + ((size_t)b * S_DIM + s) * D_DIM) + t;
        float4 v = *src;
        ushort4 o;
        o.x = f2bf(v.x); o.y = f2bf(v.y); o.z = f2bf(v.z); o.w = f2bf(v.w);
        *dst = o;
    }
}

// ---------- kernel 1b: w2 [D][U] f32 -> w2t [U][D] bf16 ----------
__global__ void transpose_w2_kernel(const float* __restrict__ w2, u16* __restrict__ w2t) {
    __shared__ float tile[32][33];
    int bx = blockIdx.x * 32, by = blockIdx.y * 32;
    int tx = threadIdx.x, ty = threadIdx.y;  // (32, 8)
    for (int i = 0; i < 32; i += 8)
        tile[ty + i][tx] = w2[(size_t)(by + ty + i) * U_DIM + bx + tx];
    __syncthreads();
    for (int i = 0; i < 32; i += 8)
        w2t[(size_t)(bx + ty + i) * D_DIM + by + tx] = f2bf(tile[tx][ty + i]);
}

// ---------- kernel 1c: qpb[b][u] = query@w1 + b1 + b2 (fp32) ----------
__global__ void qproj_kernel(const float* __restrict__ q, const float* __restrict__ w1,
                             const float* __restrict__ b1, const float* __restrict__ b2,
                             float* __restrict__ qpb) {
    int b = blockIdx.x;
    int u = blockIdx.y * 256 + threadIdx.x;
    __shared__ float ql[D_DIM];
    for (int d = threadIdx.x; d < D_DIM; d += 256) ql[d] = q[b * D_DIM + d];
    __syncthreads();
    float acc = b1[u] + b2[u];
    for (int d = 0; d < D_DIM; ++d) acc += ql[d] * w1[(size_t)d * U_DIM + u];
    qpb[b * U_DIM + u] = acc;
}

// ---------- kernel 2: compacted-row 256x256-tile, 8-wave GEMM ----------
// Race-fixed schedule: ALL staging writes are issued only AFTER the publish
// barrier of the tile in which they occur (each wave's prior-tile ds_reads
// drain before its own MFMAs, which precede its pub-barrier arrival -> no WAR).
// Pub wait is vmcnt(0): the only outstanding loads ARE tile t's 8.
__global__ __launch_bounds__(512, 2)
void score_gemm8_kernel(const u16* __restrict__ vbf, const u16* __restrict__ w2t,
                        const float* __restrict__ qpb, const float* __restrict__ vvec,
                        const int* __restrict__ idx, const int* __restrict__ cnt,
                        float* __restrict__ spart) {
    const int p    = blockIdx.x;
    const int xcd  = p & 7;
    const int slot = p >> 3;
    const int mt   = xcd * 32 + (slot >> 2);   // 0..255
    const int nt   = slot & 3;                 // 0..3
    const int bb   = mt >> 3;                  // batch
    const int lm   = mt & 7;                   // local m-tile (compacted space)
    const int n0   = nt * 256;

    const int cnt_b = cnt[bb];
    if (lm * 256 >= cnt_b) return;             // uniform exit, before any barrier

    __shared__ __align__(16) __bf16 Abuf[2][256 * 64];   // 64 KB
    __shared__ __align__(16) __bf16 Bbuf[2][256 * 64];   // 64 KB
    __shared__ float qv_lds[256], vv_lds[256];
    __shared__ float red[4][256];

    const int tid  = threadIdx.x;
    const int lane = tid & 63;
    const int wid  = tid >> 6;     // 0..7
    const int wm   = wid >> 2;     // 0..1  (M split)
    const int wn   = wid & 3;      // 0..3  (N split)

    if (tid < 256) qv_lds[tid] = qpb[bb * U_DIM + n0 + tid];
    else           vv_lds[tid - 256] = vvec[n0 + (tid - 256)];

    // staging: thread t -> LDS linear bytes [t*16, +16) (+ j*4096 per issue);
    // source column pre-swizzled; A source rows via compaction index (per-lane)
    const int tr = tid >> 3;                              // 0..63 (row within issue)
    const int sc = (((tid & 7) ^ (tr & 7)) << 3);         // swizzled source col (elems)
    const int* ib = idx + bb * S_DIM;
    const u16* vb_base = vbf + (size_t)bb * S_DIM * D_DIM + sc;
    size_t arow_off[4];
#pragma unroll
    for (int j = 0; j < 4; ++j) {
        int cp = lm * 256 + tr + j * 64;
        cp = cp < cnt_b ? cp : cnt_b - 1;                 // clamp: dup of last valid row
        arow_off[j] = (size_t)ib[cp] * D_DIM;
    }
    const u16* bsrc = w2t + (size_t)(n0 + tr) * D_DIM + sc;

    // prologue: stage K-tile 0 into buffer 0
#pragma unroll
    for (int j = 0; j < 4; ++j) {
        gload_lds16(vb_base + arow_off[j], &Abuf[0][j * 4096 + tid * 8]);
        gload_lds16(bsrc + (size_t)j * 64 * D_DIM, &Bbuf[0][j * 4096 + tid * 8]);
    }

    f32x4 acc[8][4];
#pragma unroll
    for (int mi = 0; mi < 8; ++mi)
#pragma unroll
        for (int nj = 0; nj < 4; ++nj) acc[mi][nj] = (f32x4){0.f, 0.f, 0.f, 0.f};

    const int colL = lane & 15;
    const int grp  = lane >> 4;
    const int xork = (lane & 7) << 3;
    const int kix0 = (grp * 8) ^ xork;        // kk=0 swizzled col
    const int kix1 = ((32 + grp * 8)) ^ xork; // kk=1 swizzled col
    const int arow = wm * 128 + colL;
    const int brow = wn * 64 + colL;

    bf16x8 aR[4], bR[4];

    for (int t = 0; t < 16; ++t) {
        const int cur = t & 1, nxt = cur ^ 1;
        const __bf16* Ac = Abuf[cur];
        const __bf16* Bc = Bbuf[cur];
        const size_t kofs = (size_t)(t + 1) * 64;

        // ---- publish tile t: only tile t's 8 loads are outstanding ----
        asm volatile("s_waitcnt vmcnt(0)" ::: "memory");
        __builtin_amdgcn_s_barrier();
        __builtin_amdgcn_sched_barrier(0);

        // ================= P0: reads (kk0, A mi0-3 + B); stage A01 (t+1); MFMA =========
#pragma unroll
        for (int mi = 0; mi < 4; ++mi) aR[mi] = *(const bf16x8*)&Ac[(arow + mi * 16) * 64 + kix0];
#pragma unroll
        for (int nj = 0; nj < 4; ++nj) bR[nj] = *(const bf16x8*)&Bc[(brow + nj * 16) * 64 + kix0];
        if (t < 15) {
            gload_lds16(vb_base + arow_off[0] + kofs, &Abuf[nxt][tid * 8]);
            gload_lds16(vb_base + arow_off[1] + kofs, &Abuf[nxt][4096 + tid * 8]);
        }
        __builtin_amdgcn_s_setprio(1);
#pragma unroll
        for (int mi = 0; mi < 4; ++mi)
#pragma unroll
            for (int nj = 0; nj < 4; ++nj)
                acc[mi][nj] = __builtin_amdgcn_mfma_f32_16x16x32_bf16(aR[mi], bR[nj], acc[mi][nj], 0, 0, 0);
        __builtin_amdgcn_s_setprio(0);

        // ====== P1: pre-issue reads (A mi4-7 kk0) + stage A23; barrier; MFMA ======
#pragma unroll
        for (int mi = 0; mi < 4; ++mi) aR[mi] = *(const bf16x8*)&Ac[(arow + 64 + mi * 16) * 64 + kix0];
        if (t < 15) {
            gload_lds16(vb_base + arow_off[2] + kofs, &Abuf[nxt][2 * 4096 + tid * 8]);
            gload_lds16(vb_base + arow_off[3] + kofs, &Abuf[nxt][3 * 4096 + tid * 8]);
        }
        __builtin_amdgcn_sched_barrier(0);
        __builtin_amdgcn_s_barrier();
        __builtin_amdgcn_s_setprio(1);
#pragma unroll
        for (int mi = 0; mi < 4; ++mi)
#pragma unroll
            for (int nj = 0; nj < 4; ++nj)
                acc[mi + 4][nj] = __builtin_amdgcn_mfma_f32_16x16x32_bf16(aR[mi], bR[nj], acc[mi + 4][nj], 0, 0, 0);
        __builtin_amdgcn_s_setprio(0);

        // ====== P2: pre-issue reads (kk1, A mi0-3 + B) + stage B01; barrier; MFMA ======
#pragma unroll
        for (int mi = 0; mi < 4; ++mi) aR[mi] = *(const bf16x8*)&Ac[(arow + mi * 16) * 64 + kix1];
#pragma unroll
        for (int nj = 0; nj < 4; ++nj) bR[nj] = *(const bf16x8*)&Bc[(brow + nj * 16) * 64 + kix1];
        if (t < 15) {
            gload_lds16(bsrc + kofs,                   &Bbuf[nxt][tid * 8]);
            gload_lds16(bsrc + kofs + (size_t)65536,   &Bbuf[nxt][4096 + tid * 8]);
        }
        __builtin_amdgcn_sched_barrier(0);
        __builtin_amdgcn_s_barrier();
        __builtin_amdgcn_s_setprio(1);
#pragma unroll
        for (int mi = 0; mi < 4; ++mi)
#pragma unroll
            for (int nj = 0; nj < 4; ++nj)
                acc[mi][nj] = __builtin_amdgcn_mfma_f32_16x16x32_bf16(aR[mi], bR[nj], acc[mi][nj], 0, 0, 0);
        __builtin_amdgcn_s_setprio(0);

        // ====== P3: pre-issue reads (A mi4-7 kk1) + stage B23; barrier; MFMA ======
#pragma unroll
        for (int mi = 0; mi < 4; ++mi) aR[mi] = *(const bf16x8*)&Ac[(arow + 64 + mi * 16) * 64 + kix1];
        if (t < 15) {
            gload_lds16(bsrc + kofs + (size_t)2 * 65536, &Bbuf[nxt][2 * 4096 + tid * 8]);
            gload_lds16(bsrc + kofs + (size_t)3 * 65536, &Bbuf[nxt][3 * 4096 + tid * 8]);
        }
        __builtin_amdgcn_sched_barrier(0);
        __builtin_amdgcn_s_barrier();
        __builtin_amdgcn_s_setprio(1);
#pragma unroll
        for (int mi = 0; mi < 4; ++mi)
#pragma unroll
            for (int nj = 0; nj < 4; ++nj)
                acc[mi + 4][nj] = __builtin_amdgcn_mfma_f32_16x16x32_bf16(aR[mi], bR[nj], acc[mi + 4][nj], 0, 0, 0);
        __builtin_amdgcn_s_setprio(0);
        // loop-top pub barrier closes the tile
    }

    // ---- fused epilogue: tanh(x + qpb)*v, reduce cols, scatter to original rows ----
    float rs[8][4];
#pragma unroll
    for (int mi = 0; mi < 8; ++mi)
#pragma unroll
        for (int r = 0; r < 4; ++r) rs[mi][r] = 0.f;

#pragma unroll
    for (int nj = 0; nj < 4; ++nj) {
        const int cl = wn * 64 + nj * 16 + colL;
        const float qadd = qv_lds[cl];
        const float vmul = vv_lds[cl];
#pragma unroll
        for (int mi = 0; mi < 8; ++mi)
#pragma unroll
            for (int r = 0; r < 4; ++r)
                rs[mi][r] += fast_tanh(acc[mi][nj][r] + qadd) * vmul;
    }
#pragma unroll
    for (int mi = 0; mi < 8; ++mi)
#pragma unroll
        for (int r = 0; r < 4; ++r) {
            float s = rs[mi][r];
            s += __shfl_xor(s, 1); s += __shfl_xor(s, 2);
            s += __shfl_xor(s, 4); s += __shfl_xor(s, 8);
            if (colL == 0) red[wn][wm * 128 + mi * 16 + grp * 4 + r] = s;
        }
    __syncthreads();
    if (tid < 256) {
        const int cp = lm * 256 + tid;
        if (cp < cnt_b) {
            const int orig = ib[cp];
            spart[(size_t)nt * M_TOT + bb * S_DIM + orig] =
                red[0][tid] + red[1][tid] + red[2][tid] + red[3][tid];
        }
    }
}

// ---------- fallback score kernel (fp32, no MFMA) ----------
__global__ __launch_bounds__(256)
void score_fallback_kernel(const float* __restrict__ values, const float* __restrict__ w2,
                           const float* __restrict__ qpb, const float* __restrict__ vvec,
                           float* __restrict__ spart) {
    int row0 = blockIdx.x * 16;
    int b = row0 >> 11;
    __shared__ float vr[16][D_DIM];
    for (int i = threadIdx.x; i < 16 * D_DIM; i += 256)
        vr[i >> 10][i & 1023] = values[(size_t)row0 * D_DIM + i];
    __syncthreads();
    float rs[16];
#pragma unroll
    for (int r = 0; r < 16; ++r) rs[r] = 0.f;
    for (int uu = threadIdx.x; uu < U_DIM; uu += 256) {
        float acc[16];
#pragma unroll
        for (int r = 0; r < 16; ++r) acc[r] = 0.f;
        for (int d = 0; d < D_DIM; ++d) {
            float wv = w2[(size_t)d * U_DIM + uu];
#pragma unroll
            for (int r = 0; r < 16; ++r) acc[r] += vr[r][d] * wv;
        }
        float qv = qpb[b * U_DIM + uu], vu = vvec[uu];
#pragma unroll
        for (int r = 0; r < 16; ++r) rs[r] += fast_tanh(acc[r] + qv) * vu;
    }
#pragma unroll
    for (int r = 0; r < 16; ++r) {
        float s = rs[r];
        for (int o = 1; o < 64; o <<= 1) s += __shfl_xor(s, o);
        rs[r] = s;
    }
    __shared__ float wred[16][4];
    int lane = threadIdx.x & 63, wid = threadIdx.x >> 6;
    if (lane == 0)
        for (int r = 0; r < 16; ++r) wred[r][wid] = rs[r];
    __syncthreads();
    if (threadIdx.x < 16)
        spart[row0 + threadIdx.x] = wred[threadIdx.x][0] + wred[threadIdx.x][1] +
                                    wred[threadIdx.x][2] + wred[threadIdx.x][3];
}

// ---------- kernel 3: masked softmax over S per batch ----------
__global__ void softmax_kernel(const float* __restrict__ spart, const int* __restrict__ mask,
                               float* __restrict__ wout, int nparts) {
    int b = blockIdx.x, t = threadIdx.x;
    float sc[8]; int mk[8];
    float mx = -1e30f;
#pragma unroll
    for (int i = 0; i < 8; ++i) {
        int s = t + i * 256;
        mk[i] = mask[b * S_DIM + s];
        float vsum = 0.f;
        if (mk[i])
            for (int p = 0; p < nparts; ++p) vsum += spart[(size_t)p * M_TOT + b * S_DIM + s];
        sc[i] = vsum;
        if (mk[i]) mx = fmaxf(mx, vsum);
    }
    for (int o = 1; o < 64; o <<= 1) mx = fmaxf(mx, __shfl_xor(mx, o));
    __shared__ float red[4], red2[4];
    if ((t & 63) == 0) red[t >> 6] = mx;
    __syncthreads();
    mx = fmaxf(fmaxf(red[0], red[1]), fmaxf(red[2], red[3]));
    float sum = 0.f, ev[8];
#pragma unroll
    for (int i = 0; i < 8; ++i) {
        ev[i] = mk[i] ? __expf(sc[i] - mx) : 0.f;
        sum += ev[i];
    }
    for (int o = 1; o < 64; o <<= 1) sum += __shfl_xor(sum, o);
    if ((t & 63) == 0) red2[t >> 6] = sum;
    __syncthreads();
    sum = red2[0] + red2[1] + red2[2] + red2[3];
    float inv = 1.0f / sum;
#pragma unroll
    for (int i = 0; i < 8; ++i) wout[b * S_DIM + t + i * 256] = ev[i] * inv;
}

// ---------- kernel 4: context partials over UNMASKED rows only ----------
__global__ void ctx_partial_kernel(const u16* __restrict__ vbf, const float* __restrict__ w,
                                   const int* __restrict__ idx, const int* __restrict__ cnt,
                                   float* __restrict__ part) {
    const int b = blockIdx.x, c = blockIdx.y, t = threadIdx.x;
    const int cb = cnt[b];
    const int i0 = c * 128;
    const int lim = (cb - i0) < 128 ? (cb - i0) : 128;
    const int* ib = idx + b * S_DIM;
    const u16* vb0 = vbf + (size_t)b * S_DIM * D_DIM + t * 8;
    float acc[8];
#pragma unroll
    for (int i = 0; i < 8; ++i) acc[i] = 0.f;
    for (int ii = 0; ii < lim; ++ii) {
        const int s = ib[i0 + ii];
        const float wv = w[b * S_DIM + s];
        u16x8 vv = *(const u16x8*)(vb0 + (size_t)s * D_DIM);
#pragma unroll
        for (int i = 0; i < 8; ++i) acc[i] += wv * bf2f(vv[i]);
    }
    float* pp = part + ((size_t)b * 16 + c) * D_DIM + t * 8;
#pragma unroll
    for (int i = 0; i < 8; ++i) pp[i] = acc[i];
}
// fp32 variant for fallback path
__global__ void ctx_partial_f32_kernel(const float* __restrict__ values, const float* __restrict__ w,
                                       float* __restrict__ part) {
    int b = blockIdx.x, c = blockIdx.y, t = threadIdx.x;
    const float4* vb = (const float4*)(values + ((size_t)b * S_DIM + c * 256) * D_DIM) + t;
    const float* wb = w + b * S_DIM + c * 256;
    float a0 = 0, a1 = 0, a2 = 0, a3 = 0;
    for (int s = 0; s < 256; ++s) {
        float wv = wb[s];
        float4 vv = vb[(size_t)s * 256];
        a0 += wv * vv.x; a1 += wv * vv.y; a2 += wv * vv.z; a3 += wv * vv.w;
    }
    float* pp = part + ((size_t)b * 8 + c) * D_DIM + t * 4;
    pp[0] = a0; pp[1] = a1; pp[2] = a2; pp[3] = a3;
}

// ---------- kernel 5: reduce context partials ----------
__global__ void ctx_reduce_kernel(const float* __restrict__ part, float* __restrict__ out, int nchunks) {
    int b = blockIdx.x, t = threadIdx.x;
    for (int d = t; d < D_DIM; d += 256) {
        float s = 0.f;
        for (int c = 0; c < nchunks; ++c) s += part[((size_t)b * nchunks + c) * D_DIM + d];
        out[b * D_DIM + d] = s;
    }
}

extern "C" void kernel_launch(void* const* d_in, const int* in_sizes, int n_in,
                              void* d_out, int out_size, void* d_ws, size_t ws_size,
                              hipStream_t stream) {
    const float* query  = (const float*)d_in[0];
    const float* values = (const float*)d_in[1];
    const int*   mask   = (const int*)d_in[2];
    const float* w1     = (const float*)d_in[3];
    const float* b1     = (const float*)d_in[4];
    const float* w2     = (const float*)d_in[5];
    const float* b2     = (const float*)d_in[6];
    const float* v      = (const float*)d_in[7];
    // bv (d_in[8]) shifts all scores equally -> softmax-invariant -> unused.

    float* out  = (float*)d_out;              // context [32][1024]
    float* wout = out + B_DIM * D_DIM;        // attention weights [32][2048]
    char* ws = (char*)d_ws;

    const size_t SZ_VBF = (size_t)M_TOT * D_DIM * 2;    // 134 MB bf16 values
    const size_t SZ_W2T = (size_t)U_DIM * D_DIM * 2;    // 2 MB
    const size_t SZ_QPB = (size_t)B_DIM * U_DIM * 4;    // 128 KB
    const size_t SZ_SPART = (size_t)8 * M_TOT * 4;      // 2 MB (4 used)
    const size_t SZ_PART  = (size_t)B_DIM * 16 * D_DIM * 4; // 2 MB
    const size_t SZ_IDX   = (size_t)M_TOT * 4 + 4096;   // idx + cnt
    const size_t need = SZ_VBF + SZ_W2T + SZ_QPB + SZ_SPART + SZ_PART + SZ_IDX;

    if (ws_size >= need) {
        u16*   vbf   = (u16*)ws;
        u16*   w2t   = (u16*)(ws + SZ_VBF);
        float* qpb   = (float*)(ws + SZ_VBF + SZ_W2T);
        float* spart = (float*)(ws + SZ_VBF + SZ_W2T + SZ_QPB);
        float* part  = (float*)(ws + SZ_VBF + SZ_W2T + SZ_QPB + SZ_SPART);
        int*   idx   = (int*)(ws + SZ_VBF + SZ_W2T + SZ_QPB + SZ_SPART + SZ_PART);
        int*   cnt   = idx + M_TOT;

        build_index_kernel<<<32, 256, 0, stream>>>(mask, idx, cnt);
        convert_masked_kernel<<<dim3(32, 8), 256, 0, stream>>>(values, vbf, idx, cnt);
        transpose_w2_kernel<<<dim3(32, 32), dim3(32, 8), 0, stream>>>(w2, w2t);
        qproj_kernel<<<dim3(32, 4), 256, 0, stream>>>(query, w1, b1, b2, qpb);
        score_gemm8_kernel<<<1024, 512, 0, stream>>>(vbf, w2t, qpb, v, idx, cnt, spart);
        softmax_kernel<<<32, 256, 0, stream>>>(spart, mask, wout, 4);
        ctx_partial_kernel<<<dim3(32, 16), 128, 0, stream>>>(vbf, wout, idx, cnt, part);
        ctx_reduce_kernel<<<32, 256, 0, stream>>>(part, out, 16);
    } else {
        // conservative fp32 fallback (no big scratch available)
        float* qpb   = (float*)ws;
        float* spart = (float*)(ws + SZ_QPB);
        float* part  = (float*)(ws + SZ_QPB + (size_t)M_TOT * 4);
        qproj_kernel<<<dim3(32, 4), 256, 0, stream>>>(query, w1, b1, b2, qpb);
        score_fallback_kernel<<<4096, 256, 0, stream>>>(values, w2, qpb, v, spart);
        softmax_kernel<<<32, 256, 0, stream>>>(spart, mask, wout, 1);
        ctx_partial_f32_kernel<<<dim3(32, 8), 256, 0, stream>>>(values, wout, part);
        ctx_reduce_kernel<<<32, 256, 0, stream>>>(part, out, 8);
    }
}

// Round 12
// 255.340 us; speedup vs baseline: 1.2718x; 1.2718x over previous
//
#include <hip/hip_runtime.h>
#include <cstdint>

typedef unsigned short u16;
typedef __bf16 bf16x8 __attribute__((ext_vector_type(8)));
typedef float f32x4 __attribute__((ext_vector_type(4)));
typedef u16 u16x8 __attribute__((ext_vector_type(8)));

#define B_DIM 32
#define S_DIM 2048
#define D_DIM 1024
#define U_DIM 1024
#define M_TOT (B_DIM * S_DIM)   // 65536 rows

// ---------- helpers ----------
__device__ __forceinline__ u16 f2bf(float f) {
    union { float f; uint32_t u; } a; a.f = f;
    uint32_t u = a.u;
    uint32_t r = (u + 0x7FFFu + ((u >> 16) & 1u)) >> 16;   // RNE
    return (u16)r;
}
__device__ __forceinline__ float bf2f(u16 h) {
    union { uint32_t u; float f; } a; a.u = ((uint32_t)h) << 16;
    return a.f;
}
__device__ __forceinline__ float fast_tanh(float x) {
    float ax = fabsf(x);
    float e  = __expf(-2.0f * ax);
    float th = __fdividef(1.0f - e, 1.0f + e);
    return copysignf(th, x);
}
// global -> LDS async copy, 16B per lane
__device__ __forceinline__ void gload_lds16(const void* g, void* l) {
    __builtin_amdgcn_global_load_lds(
        (__attribute__((address_space(1))) void*)(uintptr_t)g,
        (__attribute__((address_space(3))) void*)(uint32_t)(uintptr_t)l,
        16, 0, 0);
}

// ---------- kernel 0: per-batch compaction of unmasked rows ----------
__global__ void build_index_kernel(const int* __restrict__ mask, int* __restrict__ idx,
                                   int* __restrict__ cnt) {
    const int b = blockIdx.x, t = threadIdx.x;
    __shared__ int wsum[4];
    const int base = t * 8;
    int m[8]; int c = 0;
#pragma unroll
    for (int i = 0; i < 8; ++i) { m[i] = mask[b * S_DIM + base + i] != 0; c += m[i]; }
    const int lane = t & 63, w = t >> 6;
    int pre = c;
    for (int o = 1; o < 64; o <<= 1) { int v = __shfl_up(pre, o); if (lane >= o) pre += v; }
    if (lane == 63) wsum[w] = pre;
    __syncthreads();
    int woff = 0;
    for (int i = 0; i < w; ++i) woff += wsum[i];
    int excl = woff + pre - c;
#pragma unroll
    for (int i = 0; i < 8; ++i) if (m[i]) idx[b * S_DIM + excl++] = base + i;
    if (t == 255) cnt[b] = woff + pre;
}

// ---------- kernel 1a: values f32 -> bf16, UNMASKED rows only ----------
// grid (32, 64), 256 threads: block (b,c) grid-strides compacted rows c, c+64, ...
// 2048 blocks -> full occupancy; each row = coalesced float4 read + ushort4 write.
__global__ void convert_masked_kernel(const float* __restrict__ values, u16* __restrict__ vbf,
                                      const int* __restrict__ idx, const int* __restrict__ cnt) {
    const int b = blockIdx.x, c = blockIdx.y, t = threadIdx.x;
    const int cb = cnt[b];
    const int* ib = idx + b * S_DIM;
    for (int ii = c; ii < cb; ii += 64) {
        const int s = ib[ii];
        const float4* src = (const float4*)(values + ((size_t)b * S_DIM + s) * D_DIM) + t;
        ushort4* dst = (ushort4*)(vbf + ((size_t)b * S_DIM + s) * D_DIM) + t;
        float4 v = *src;
        ushort4 o;
        o.x = f2bf(v.x); o.y = f2bf(v.y); o.z = f2bf(v.z); o.w = f2bf(v.w);
        *dst = o;
    }
}

// ---------- kernel 1b: w2 [D][U] f32 -> w2t [U][D] bf16 ----------
__global__ void transpose_w2_kernel(const float* __restrict__ w2, u16* __restrict__ w2t) {
    __shared__ float tile[32][33];
    int bx = blockIdx.x * 32, by = blockIdx.y * 32;
    int tx = threadIdx.x, ty = threadIdx.y;  // (32, 8)
    for (int i = 0; i < 32; i += 8)
        tile[ty + i][tx] = w2[(size_t)(by + ty + i) * U_DIM + bx + tx];
    __syncthreads();
    for (int i = 0; i < 32; i += 8)
        w2t[(size_t)(bx + ty + i) * D_DIM + by + tx] = f2bf(tile[tx][ty + i]);
}

// ---------- kernel 1c: qpb[b][u] = query@w1 + b1 + b2 (fp32) ----------
__global__ void qproj_kernel(const float* __restrict__ q, const float* __restrict__ w1,
                             const float* __restrict__ b1, const float* __restrict__ b2,
                             float* __restrict__ qpb) {
    int b = blockIdx.x;
    int u = blockIdx.y * 256 + threadIdx.x;
    __shared__ float ql[D_DIM];
    for (int d = threadIdx.x; d < D_DIM; d += 256) ql[d] = q[b * D_DIM + d];
    __syncthreads();
    float acc = b1[u] + b2[u];
    for (int d = 0; d < D_DIM; ++d) acc += ql[d] * w1[(size_t)d * U_DIM + u];
    qpb[b * U_DIM + u] = acc;
}

// ---------- kernel 2: compacted-row 256x256-tile, 8-wave GEMM ----------
// Race-fixed schedule (round 11, passed): ALL staging writes are issued only
// AFTER the publish barrier of the tile in which they occur. Pub wait vmcnt(0)
// (the only outstanding loads ARE tile t's 8 -> not a pipeline drain).
__global__ __launch_bounds__(512, 2)
void score_gemm8_kernel(const u16* __restrict__ vbf, const u16* __restrict__ w2t,
                        const float* __restrict__ qpb, const float* __restrict__ vvec,
                        const int* __restrict__ idx, const int* __restrict__ cnt,
                        float* __restrict__ spart) {
    const int p    = blockIdx.x;
    const int xcd  = p & 7;
    const int slot = p >> 3;
    const int mt   = xcd * 32 + (slot >> 2);   // 0..255
    const int nt   = slot & 3;                 // 0..3
    const int bb   = mt >> 3;                  // batch
    const int lm   = mt & 7;                   // local m-tile (compacted space)
    const int n0   = nt * 256;

    const int cnt_b = cnt[bb];
    if (lm * 256 >= cnt_b) return;             // uniform exit, before any barrier

    __shared__ __align__(16) __bf16 Abuf[2][256 * 64];   // 64 KB
    __shared__ __align__(16) __bf16 Bbuf[2][256 * 64];   // 64 KB
    __shared__ float qv_lds[256], vv_lds[256];
    __shared__ float red[4][256];

    const int tid  = threadIdx.x;
    const int lane = tid & 63;
    const int wid  = tid >> 6;     // 0..7
    const int wm   = wid >> 2;     // 0..1  (M split)
    const int wn   = wid & 3;      // 0..3  (N split)

    if (tid < 256) qv_lds[tid] = qpb[bb * U_DIM + n0 + tid];
    else           vv_lds[tid - 256] = vvec[n0 + (tid - 256)];

    // staging: thread t -> LDS linear bytes [t*16, +16) (+ j*4096 per issue);
    // source column pre-swizzled; A source rows via compaction index (per-lane)
    const int tr = tid >> 3;                              // 0..63 (row within issue)
    const int sc = (((tid & 7) ^ (tr & 7)) << 3);         // swizzled source col (elems)
    const int* ib = idx + bb * S_DIM;
    const u16* vb_base = vbf + (size_t)bb * S_DIM * D_DIM + sc;
    size_t arow_off[4];
#pragma unroll
    for (int j = 0; j < 4; ++j) {
        int cp = lm * 256 + tr + j * 64;
        cp = cp < cnt_b ? cp : cnt_b - 1;                 // clamp: dup of last valid row
        arow_off[j] = (size_t)ib[cp] * D_DIM;
    }
    const u16* bsrc = w2t + (size_t)(n0 + tr) * D_DIM + sc;

    // prologue: stage K-tile 0 into buffer 0
#pragma unroll
    for (int j = 0; j < 4; ++j) {
        gload_lds16(vb_base + arow_off[j], &Abuf[0][j * 4096 + tid * 8]);
        gload_lds16(bsrc + (size_t)j * 64 * D_DIM, &Bbuf[0][j * 4096 + tid * 8]);
    }

    f32x4 acc[8][4];
#pragma unroll
    for (int mi = 0; mi < 8; ++mi)
#pragma unroll
        for (int nj = 0; nj < 4; ++nj) acc[mi][nj] = (f32x4){0.f, 0.f, 0.f, 0.f};

    const int colL = lane & 15;
    const int grp  = lane >> 4;
    const int xork = (lane & 7) << 3;
    const int kix0 = (grp * 8) ^ xork;        // kk=0 swizzled col
    const int kix1 = ((32 + grp * 8)) ^ xork; // kk=1 swizzled col
    const int arow = wm * 128 + colL;
    const int brow = wn * 64 + colL;

    bf16x8 aR[4], bR[4];

    for (int t = 0; t < 16; ++t) {
        const int cur = t & 1, nxt = cur ^ 1;
        const __bf16* Ac = Abuf[cur];
        const __bf16* Bc = Bbuf[cur];
        const size_t kofs = (size_t)(t + 1) * 64;

        // ---- publish tile t: only tile t's 8 loads are outstanding ----
        asm volatile("s_waitcnt vmcnt(0)" ::: "memory");
        __builtin_amdgcn_s_barrier();
        __builtin_amdgcn_sched_barrier(0);

        // ================= P0: reads (kk0, A mi0-3 + B); stage A01 (t+1); MFMA =========
#pragma unroll
        for (int mi = 0; mi < 4; ++mi) aR[mi] = *(const bf16x8*)&Ac[(arow + mi * 16) * 64 + kix0];
#pragma unroll
        for (int nj = 0; nj < 4; ++nj) bR[nj] = *(const bf16x8*)&Bc[(brow + nj * 16) * 64 + kix0];
        if (t < 15) {
            gload_lds16(vb_base + arow_off[0] + kofs, &Abuf[nxt][tid * 8]);
            gload_lds16(vb_base + arow_off[1] + kofs, &Abuf[nxt][4096 + tid * 8]);
        }
        __builtin_amdgcn_s_setprio(1);
#pragma unroll
        for (int mi = 0; mi < 4; ++mi)
#pragma unroll
            for (int nj = 0; nj < 4; ++nj)
                acc[mi][nj] = __builtin_amdgcn_mfma_f32_16x16x32_bf16(aR[mi], bR[nj], acc[mi][nj], 0, 0, 0);
        __builtin_amdgcn_s_setprio(0);

        // ====== P1: pre-issue reads (A mi4-7 kk0) + stage A23; barrier; MFMA ======
#pragma unroll
        for (int mi = 0; mi < 4; ++mi) aR[mi] = *(const bf16x8*)&Ac[(arow + 64 + mi * 16) * 64 + kix0];
        if (t < 15) {
            gload_lds16(vb_base + arow_off[2] + kofs, &Abuf[nxt][2 * 4096 + tid * 8]);
            gload_lds16(vb_base + arow_off[3] + kofs, &Abuf[nxt][3 * 4096 + tid * 8]);
        }
        __builtin_amdgcn_sched_barrier(0);
        __builtin_amdgcn_s_barrier();
        __builtin_amdgcn_s_setprio(1);
#pragma unroll
        for (int mi = 0; mi < 4; ++mi)
#pragma unroll
            for (int nj = 0; nj < 4; ++nj)
                acc[mi + 4][nj] = __builtin_amdgcn_mfma_f32_16x16x32_bf16(aR[mi], bR[nj], acc[mi + 4][nj], 0, 0, 0);
        __builtin_amdgcn_s_setprio(0);

        // ====== P2: pre-issue reads (kk1, A mi0-3 + B) + stage B01; barrier; MFMA ======
#pragma unroll
        for (int mi = 0; mi < 4; ++mi) aR[mi] = *(const bf16x8*)&Ac[(arow + mi * 16) * 64 + kix1];
#pragma unroll
        for (int nj = 0; nj < 4; ++nj) bR[nj] = *(const bf16x8*)&Bc[(brow + nj * 16) * 64 + kix1];
        if (t < 15) {
            gload_lds16(bsrc + kofs,                   &Bbuf[nxt][tid * 8]);
            gload_lds16(bsrc + kofs + (size_t)65536,   &Bbuf[nxt][4096 + tid * 8]);
        }
        __builtin_amdgcn_sched_barrier(0);
        __builtin_amdgcn_s_barrier();
        __builtin_amdgcn_s_setprio(1);
#pragma unroll
        for (int mi = 0; mi < 4; ++mi)
#pragma unroll
            for (int nj = 0; nj < 4; ++nj)
                acc[mi][nj] = __builtin_amdgcn_mfma_f32_16x16x32_bf16(aR[mi], bR[nj], acc[mi][nj], 0, 0, 0);
        __builtin_amdgcn_s_setprio(0);

        // ====== P3: pre-issue reads (A mi4-7 kk1) + stage B23; barrier; MFMA ======
#pragma unroll
        for (int mi = 0; mi < 4; ++mi) aR[mi] = *(const bf16x8*)&Ac[(arow + 64 + mi * 16) * 64 + kix1];
        if (t < 15) {
            gload_lds16(bsrc + kofs + (size_t)2 * 65536, &Bbuf[nxt][2 * 4096 + tid * 8]);
            gload_lds16(bsrc + kofs + (size_t)3 * 65536, &Bbuf[nxt][3 * 4096 + tid * 8]);
        }
        __builtin_amdgcn_sched_barrier(0);
        __builtin_amdgcn_s_barrier();
        __builtin_amdgcn_s_setprio(1);
#pragma unroll
        for (int mi = 0; mi < 4; ++mi)
#pragma unroll
            for (int nj = 0; nj < 4; ++nj)
                acc[mi + 4][nj] = __builtin_amdgcn_mfma_f32_16x16x32_bf16(aR[mi], bR[nj], acc[mi + 4][nj], 0, 0, 0);
        __builtin_amdgcn_s_setprio(0);
        // loop-top pub barrier closes the tile
    }

    // ---- fused epilogue: tanh(x + qpb)*v, reduce cols, scatter to original rows ----
    float rs[8][4];
#pragma unroll
    for (int mi = 0; mi < 8; ++mi)
#pragma unroll
        for (int r = 0; r < 4; ++r) rs[mi][r] = 0.f;

#pragma unroll
    for (int nj = 0; nj < 4; ++nj) {
        const int cl = wn * 64 + nj * 16 + colL;
        const float qadd = qv_lds[cl];
        const float vmul = vv_lds[cl];
#pragma unroll
        for (int mi = 0; mi < 8; ++mi)
#pragma unroll
            for (int r = 0; r < 4; ++r)
                rs[mi][r] += fast_tanh(acc[mi][nj][r] + qadd) * vmul;
    }
#pragma unroll
    for (int mi = 0; mi < 8; ++mi)
#pragma unroll
        for (int r = 0; r < 4; ++r) {
            float s = rs[mi][r];
            s += __shfl_xor(s, 1); s += __shfl_xor(s, 2);
            s += __shfl_xor(s, 4); s += __shfl_xor(s, 8);
            if (colL == 0) red[wn][wm * 128 + mi * 16 + grp * 4 + r] = s;
        }
    __syncthreads();
    if (tid < 256) {
        const int cp = lm * 256 + tid;
        if (cp < cnt_b) {
            const int orig = ib[cp];
            spart[(size_t)nt * M_TOT + bb * S_DIM + orig] =
                red[0][tid] + red[1][tid] + red[2][tid] + red[3][tid];
        }
    }
}

// ---------- fallback score kernel (fp32, no MFMA) ----------
__global__ __launch_bounds__(256)
void score_fallback_kernel(const float* __restrict__ values, const float* __restrict__ w2,
                           const float* __restrict__ qpb, const float* __restrict__ vvec,
                           float* __restrict__ spart) {
    int row0 = blockIdx.x * 16;
    int b = row0 >> 11;
    __shared__ float vr[16][D_DIM];
    for (int i = threadIdx.x; i < 16 * D_DIM; i += 256)
        vr[i >> 10][i & 1023] = values[(size_t)row0 * D_DIM + i];
    __syncthreads();
    float rs[16];
#pragma unroll
    for (int r = 0; r < 16; ++r) rs[r] = 0.f;
    for (int uu = threadIdx.x; uu < U_DIM; uu += 256) {
        float acc[16];
#pragma unroll
        for (int r = 0; r < 16; ++r) acc[r] = 0.f;
        for (int d = 0; d < D_DIM; ++d) {
            float wv = w2[(size_t)d * U_DIM + uu];
#pragma unroll
            for (int r = 0; r < 16; ++r) acc[r] += vr[r][d] * wv;
        }
        float qv = qpb[b * U_DIM + uu], vu = vvec[uu];
#pragma unroll
        for (int r = 0; r < 16; ++r) rs[r] += fast_tanh(acc[r] + qv) * vu;
    }
#pragma unroll
    for (int r = 0; r < 16; ++r) {
        float s = rs[r];
        for (int o = 1; o < 64; o <<= 1) s += __shfl_xor(s, o);
        rs[r] = s;
    }
    __shared__ float wred[16][4];
    int lane = threadIdx.x & 63, wid = threadIdx.x >> 6;
    if (lane == 0)
        for (int r = 0; r < 16; ++r) wred[r][wid] = rs[r];
    __syncthreads();
    if (threadIdx.x < 16)
        spart[row0 + threadIdx.x] = wred[threadIdx.x][0] + wred[threadIdx.x][1] +
                                    wred[threadIdx.x][2] + wred[threadIdx.x][3];
}

// ---------- kernel 3: masked softmax over S per batch ----------
__global__ void softmax_kernel(const float* __restrict__ spart, const int* __restrict__ mask,
                               float* __restrict__ wout, int nparts) {
    int b = blockIdx.x, t = threadIdx.x;
    float sc[8]; int mk[8];
    float mx = -1e30f;
#pragma unroll
    for (int i = 0; i < 8; ++i) {
        int s = t + i * 256;
        mk[i] = mask[b * S_DIM + s];
        float vsum = 0.f;
        if (mk[i])
            for (int p = 0; p < nparts; ++p) vsum += spart[(size_t)p * M_TOT + b * S_DIM + s];
        sc[i] = vsum;
        if (mk[i]) mx = fmaxf(mx, vsum);
    }
    for (int o = 1; o < 64; o <<= 1) mx = fmaxf(mx, __shfl_xor(mx, o));
    __shared__ float red[4], red2[4];
    if ((t & 63) == 0) red[t >> 6] = mx;
    __syncthreads();
    mx = fmaxf(fmaxf(red[0], red[1]), fmaxf(red[2], red[3]));
    float sum = 0.f, ev[8];
#pragma unroll
    for (int i = 0; i < 8; ++i) {
        ev[i] = mk[i] ? __expf(sc[i] - mx) : 0.f;
        sum += ev[i];
    }
    for (int o = 1; o < 64; o <<= 1) sum += __shfl_xor(sum, o);
    if ((t & 63) == 0) red2[t >> 6] = sum;
    __syncthreads();
    sum = red2[0] + red2[1] + red2[2] + red2[3];
    float inv = 1.0f / sum;
#pragma unroll
    for (int i = 0; i < 8; ++i) wout[b * S_DIM + t + i * 256] = ev[i] * inv;
}

// ---------- kernel 4: context partials over UNMASKED rows only ----------
__global__ void ctx_partial_kernel(const u16* __restrict__ vbf, const float* __restrict__ w,
                                   const int* __restrict__ idx, const int* __restrict__ cnt,
                                   float* __restrict__ part) {
    const int b = blockIdx.x, c = blockIdx.y, t = threadIdx.x;
    const int cb = cnt[b];
    const int i0 = c * 128;
    const int lim = (cb - i0) < 128 ? (cb - i0) : 128;
    const int* ib = idx + b * S_DIM;
    const u16* vb0 = vbf + (size_t)b * S_DIM * D_DIM + t * 8;
    float acc[8];
#pragma unroll
    for (int i = 0; i < 8; ++i) acc[i] = 0.f;
    for (int ii = 0; ii < lim; ++ii) {
        const int s = ib[i0 + ii];
        const float wv = w[b * S_DIM + s];
        u16x8 vv = *(const u16x8*)(vb0 + (size_t)s * D_DIM);
#pragma unroll
        for (int i = 0; i < 8; ++i) acc[i] += wv * bf2f(vv[i]);
    }
    float* pp = part + ((size_t)b * 16 + c) * D_DIM + t * 8;
#pragma unroll
    for (int i = 0; i < 8; ++i) pp[i] = acc[i];
}
// fp32 variant for fallback path
__global__ void ctx_partial_f32_kernel(const float* __restrict__ values, const float* __restrict__ w,
                                       float* __restrict__ part) {
    int b = blockIdx.x, c = blockIdx.y, t = threadIdx.x;
    const float4* vb = (const float4*)(values + ((size_t)b * S_DIM + c * 256) * D_DIM) + t;
    const float* wb = w + b * S_DIM + c * 256;
    float a0 = 0, a1 = 0, a2 = 0, a3 = 0;
    for (int s = 0; s < 256; ++s) {
        float wv = wb[s];
        float4 vv = vb[(size_t)s * 256];
        a0 += wv * vv.x; a1 += wv * vv.y; a2 += wv * vv.z; a3 += wv * vv.w;
    }
    float* pp = part + ((size_t)b * 8 + c) * D_DIM + t * 4;
    pp[0] = a0; pp[1] = a1; pp[2] = a2; pp[3] = a3;
}

// ---------- kernel 5: reduce context partials ----------
__global__ void ctx_reduce_kernel(const float* __restrict__ part, float* __restrict__ out, int nchunks) {
    int b = blockIdx.x, t = threadIdx.x;
    for (int d = t; d < D_DIM; d += 256) {
        float s = 0.f;
        for (int c = 0; c < nchunks; ++c) s += part[((size_t)b * nchunks + c) * D_DIM + d];
        out[b * D_DIM + d] = s;
    }
}

extern "C" void kernel_launch(void* const* d_in, const int* in_sizes, int n_in,
                              void* d_out, int out_size, void* d_ws, size_t ws_size,
                              hipStream_t stream) {
    const float* query  = (const float*)d_in[0];
    const float* values = (const float*)d_in[1];
    const int*   mask   = (const int*)d_in[2];
    const float* w1     = (const float*)d_in[3];
    const float* b1     = (const float*)d_in[4];
    const float* w2     = (const float*)d_in[5];
    const float* b2     = (const float*)d_in[6];
    const float* v      = (const float*)d_in[7];
    // bv (d_in[8]) shifts all scores equally -> softmax-invariant -> unused.

    float* out  = (float*)d_out;              // context [32][1024]
    float* wout = out + B_DIM * D_DIM;        // attention weights [32][2048]
    char* ws = (char*)d_ws;

    const size_t SZ_VBF = (size_t)M_TOT * D_DIM * 2;    // 134 MB bf16 values
    const size_t SZ_W2T = (size_t)U_DIM * D_DIM * 2;    // 2 MB
    const size_t SZ_QPB = (size_t)B_DIM * U_DIM * 4;    // 128 KB
    const size_t SZ_SPART = (size_t)8 * M_TOT * 4;      // 2 MB (4 used)
    const size_t SZ_PART  = (size_t)B_DIM * 16 * D_DIM * 4; // 2 MB
    const size_t SZ_IDX   = (size_t)M_TOT * 4 + 4096;   // idx + cnt
    const size_t need = SZ_VBF + SZ_W2T + SZ_QPB + SZ_SPART + SZ_PART + SZ_IDX;

    if (ws_size >= need) {
        u16*   vbf   = (u16*)ws;
        u16*   w2t   = (u16*)(ws + SZ_VBF);
        float* qpb   = (float*)(ws + SZ_VBF + SZ_W2T);
        float* spart = (float*)(ws + SZ_VBF + SZ_W2T + SZ_QPB);
        float* part  = (float*)(ws + SZ_VBF + SZ_W2T + SZ_QPB + SZ_SPART);
        int*   idx   = (int*)(ws + SZ_VBF + SZ_W2T + SZ_QPB + SZ_SPART + SZ_PART);
        int*   cnt   = idx + M_TOT;

        build_index_kernel<<<32, 256, 0, stream>>>(mask, idx, cnt);
        convert_masked_kernel<<<dim3(32, 64), 256, 0, stream>>>(values, vbf, idx, cnt);
        transpose_w2_kernel<<<dim3(32, 32), dim3(32, 8), 0, stream>>>(w2, w2t);
        qproj_kernel<<<dim3(32, 4), 256, 0, stream>>>(query, w1, b1, b2, qpb);
        score_gemm8_kernel<<<1024, 512, 0, stream>>>(vbf, w2t, qpb, v, idx, cnt, spart);
        softmax_kernel<<<32, 256, 0, stream>>>(spart, mask, wout, 4);
        ctx_partial_kernel<<<dim3(32, 16), 128, 0, stream>>>(vbf, wout, idx, cnt, part);
        ctx_reduce_kernel<<<32, 256, 0, stream>>>(part, out, 16);
    } else {
        // conservative fp32 fallback (no big scratch available)
        float* qpb   = (float*)ws;
        float* spart = (float*)(ws + SZ_QPB);
        float* part  = (float*)(ws + SZ_QPB + (size_t)M_TOT * 4);
        qproj_kernel<<<dim3(32, 4), 256, 0, stream>>>(query, w1, b1, b2, qpb);
        score_fallback_kernel<<<4096, 256, 0, stream>>>(values, w2, qpb, v, spart);
        softmax_kernel<<<32, 256, 0, stream>>>(spart, mask, wout, 1);
        ctx_partial_f32_kernel<<<dim3(32, 8), 256, 0, stream>>>(values, wout, part);
        ctx_reduce_kernel<<<32, 256, 0, stream>>>(part, out, 8);
    }
}

// Round 13
// 227.505 us; speedup vs baseline: 1.4274x; 1.1223x over previous
//
#include <hip/hip_runtime.h>
#include <cstdint>

typedef unsigned short u16;
typedef __bf16 bf16x8 __attribute__((ext_vector_type(8)));
typedef float f32x4 __attribute__((ext_vector_type(4)));
typedef u16 u16x8 __attribute__((ext_vector_type(8)));

#define B_DIM 32
#define S_DIM 2048
#define D_DIM 1024
#define U_DIM 1024
#define M_TOT (B_DIM * S_DIM)   // 65536 rows

// ---------- helpers ----------
__device__ __forceinline__ u16 f2bf(float f) {
    union { float f; uint32_t u; } a; a.f = f;
    uint32_t u = a.u;
    uint32_t r = (u + 0x7FFFu + ((u >> 16) & 1u)) >> 16;   // RNE
    return (u16)r;
}
__device__ __forceinline__ float bf2f(u16 h) {
    union { uint32_t u; float f; } a; a.u = ((uint32_t)h) << 16;
    return a.f;
}
__device__ __forceinline__ float fast_tanh(float x) {
    float ax = fabsf(x);
    float e  = __expf(-2.0f * ax);
    float th = __fdividef(1.0f - e, 1.0f + e);
    return copysignf(th, x);
}
// global -> LDS async copy, 16B per lane
__device__ __forceinline__ void gload_lds16(const void* g, void* l) {
    __builtin_amdgcn_global_load_lds(
        (__attribute__((address_space(1))) void*)(uintptr_t)g,
        (__attribute__((address_space(3))) void*)(uint32_t)(uintptr_t)l,
        16, 0, 0);
}

// ---------- kernel 0: per-batch compaction of unmasked rows ----------
__global__ void build_index_kernel(const int* __restrict__ mask, int* __restrict__ idx,
                                   int* __restrict__ cnt) {
    const int b = blockIdx.x, t = threadIdx.x;
    __shared__ int wsum[4];
    const int base = t * 8;
    int m[8]; int c = 0;
#pragma unroll
    for (int i = 0; i < 8; ++i) { m[i] = mask[b * S_DIM + base + i] != 0; c += m[i]; }
    const int lane = t & 63, w = t >> 6;
    int pre = c;
    for (int o = 1; o < 64; o <<= 1) { int v = __shfl_up(pre, o); if (lane >= o) pre += v; }
    if (lane == 63) wsum[w] = pre;
    __syncthreads();
    int woff = 0;
    for (int i = 0; i < w; ++i) woff += wsum[i];
    int excl = woff + pre - c;
#pragma unroll
    for (int i = 0; i < 8; ++i) if (m[i]) idx[b * S_DIM + excl++] = base + i;
    if (t == 255) cnt[b] = woff + pre;
}

// ---------- kernel 1a: values f32 -> bf16, UNMASKED rows only ----------
// grid (32, 64), 256 threads: block (b,c) grid-strides compacted rows c, c+64, ...
__global__ void convert_masked_kernel(const float* __restrict__ values, u16* __restrict__ vbf,
                                      const int* __restrict__ idx, const int* __restrict__ cnt) {
    const int b = blockIdx.x, c = blockIdx.y, t = threadIdx.x;
    const int cb = cnt[b];
    const int* ib = idx + b * S_DIM;
    for (int ii = c; ii < cb; ii += 64) {
        const int s = ib[ii];
        const float4* src = (const float4*)(values + ((size_t)b * S_DIM + s) * D_DIM) + t;
        ushort4* dst = (ushort4*)(vbf + ((size_t)b * S_DIM + s) * D_DIM) + t;
        float4 v = *src;
        ushort4 o;
        o.x = f2bf(v.x); o.y = f2bf(v.y); o.z = f2bf(v.z); o.w = f2bf(v.w);
        *dst = o;
    }
}

// ---------- kernel 1b: w2 [D][U] f32 -> w2t [U][D] bf16 ----------
__global__ void transpose_w2_kernel(const float* __restrict__ w2, u16* __restrict__ w2t) {
    __shared__ float tile[32][33];
    int bx = blockIdx.x * 32, by = blockIdx.y * 32;
    int tx = threadIdx.x, ty = threadIdx.y;  // (32, 8)
    for (int i = 0; i < 32; i += 8)
        tile[ty + i][tx] = w2[(size_t)(by + ty + i) * U_DIM + bx + tx];
    __syncthreads();
    for (int i = 0; i < 32; i += 8)
        w2t[(size_t)(bx + ty + i) * D_DIM + by + tx] = f2bf(tile[tx][ty + i]);
}

// ---------- kernel 1c: qpb = query@w1 + b1 + b2 (parallel-d, 1024 blocks) ----------
// grid (32, 32), 256 threads: block (b, uc) computes u in [uc*32, +32);
// thread (ul, dg) accumulates d-range [dg*128, +128); LDS reduce over 8 dg.
__global__ void qproj_kernel(const float* __restrict__ q, const float* __restrict__ w1,
                             const float* __restrict__ b1, const float* __restrict__ b2,
                             float* __restrict__ qpb) {
    const int b = blockIdx.x, uc = blockIdx.y;
    const int u0 = uc * 32;
    const int ul = threadIdx.x & 31;
    const int dg = threadIdx.x >> 5;   // 0..7
    __shared__ float ql[D_DIM];
    __shared__ float red[8][32];
    for (int d = threadIdx.x; d < D_DIM; d += 256) ql[d] = q[b * D_DIM + d];
    __syncthreads();
    float acc = 0.f;
    const int d0 = dg * 128;
    for (int d = d0; d < d0 + 128; ++d)
        acc += ql[d] * w1[(size_t)d * U_DIM + u0 + ul];
    red[dg][ul] = acc;
    __syncthreads();
    if (threadIdx.x < 32) {
        float s = b1[u0 + ul] + b2[u0 + ul];
#pragma unroll
        for (int g = 0; g < 8; ++g) s += red[g][ul];
        qpb[b * U_DIM + u0 + ul] = s;
    }
}

// ---------- kernel 2: compacted-row 256x256-tile, 8-wave GEMM (round-11, UNCHANGED) ----------
__global__ __launch_bounds__(512, 2)
void score_gemm8_kernel(const u16* __restrict__ vbf, const u16* __restrict__ w2t,
                        const float* __restrict__ qpb, const float* __restrict__ vvec,
                        const int* __restrict__ idx, const int* __restrict__ cnt,
                        float* __restrict__ spart) {
    const int p    = blockIdx.x;
    const int xcd  = p & 7;
    const int slot = p >> 3;
    const int mt   = xcd * 32 + (slot >> 2);   // 0..255
    const int nt   = slot & 3;                 // 0..3
    const int bb   = mt >> 3;                  // batch
    const int lm   = mt & 7;                   // local m-tile (compacted space)
    const int n0   = nt * 256;

    const int cnt_b = cnt[bb];
    if (lm * 256 >= cnt_b) return;             // uniform exit, before any barrier

    __shared__ __align__(16) __bf16 Abuf[2][256 * 64];   // 64 KB
    __shared__ __align__(16) __bf16 Bbuf[2][256 * 64];   // 64 KB
    __shared__ float qv_lds[256], vv_lds[256];
    __shared__ float red[4][256];

    const int tid  = threadIdx.x;
    const int lane = tid & 63;
    const int wid  = tid >> 6;     // 0..7
    const int wm   = wid >> 2;     // 0..1  (M split)
    const int wn   = wid & 3;      // 0..3  (N split)

    if (tid < 256) qv_lds[tid] = qpb[bb * U_DIM + n0 + tid];
    else           vv_lds[tid - 256] = vvec[n0 + (tid - 256)];

    const int tr = tid >> 3;                              // 0..63 (row within issue)
    const int sc = (((tid & 7) ^ (tr & 7)) << 3);         // swizzled source col (elems)
    const int* ib = idx + bb * S_DIM;
    const u16* vb_base = vbf + (size_t)bb * S_DIM * D_DIM + sc;
    size_t arow_off[4];
#pragma unroll
    for (int j = 0; j < 4; ++j) {
        int cp = lm * 256 + tr + j * 64;
        cp = cp < cnt_b ? cp : cnt_b - 1;                 // clamp: dup of last valid row
        arow_off[j] = (size_t)ib[cp] * D_DIM;
    }
    const u16* bsrc = w2t + (size_t)(n0 + tr) * D_DIM + sc;

    // prologue: stage K-tile 0 into buffer 0
#pragma unroll
    for (int j = 0; j < 4; ++j) {
        gload_lds16(vb_base + arow_off[j], &Abuf[0][j * 4096 + tid * 8]);
        gload_lds16(bsrc + (size_t)j * 64 * D_DIM, &Bbuf[0][j * 4096 + tid * 8]);
    }

    f32x4 acc[8][4];
#pragma unroll
    for (int mi = 0; mi < 8; ++mi)
#pragma unroll
        for (int nj = 0; nj < 4; ++nj) acc[mi][nj] = (f32x4){0.f, 0.f, 0.f, 0.f};

    const int colL = lane & 15;
    const int grp  = lane >> 4;
    const int xork = (lane & 7) << 3;
    const int kix0 = (grp * 8) ^ xork;        // kk=0 swizzled col
    const int kix1 = ((32 + grp * 8)) ^ xork; // kk=1 swizzled col
    const int arow = wm * 128 + colL;
    const int brow = wn * 64 + colL;

    bf16x8 aR[4], bR[4];

    for (int t = 0; t < 16; ++t) {
        const int cur = t & 1, nxt = cur ^ 1;
        const __bf16* Ac = Abuf[cur];
        const __bf16* Bc = Bbuf[cur];
        const size_t kofs = (size_t)(t + 1) * 64;

        // ---- publish tile t: only tile t's 8 loads are outstanding ----
        asm volatile("s_waitcnt vmcnt(0)" ::: "memory");
        __builtin_amdgcn_s_barrier();
        __builtin_amdgcn_sched_barrier(0);

        // ================= P0: reads (kk0, A mi0-3 + B); stage A01 (t+1); MFMA =========
#pragma unroll
        for (int mi = 0; mi < 4; ++mi) aR[mi] = *(const bf16x8*)&Ac[(arow + mi * 16) * 64 + kix0];
#pragma unroll
        for (int nj = 0; nj < 4; ++nj) bR[nj] = *(const bf16x8*)&Bc[(brow + nj * 16) * 64 + kix0];
        if (t < 15) {
            gload_lds16(vb_base + arow_off[0] + kofs, &Abuf[nxt][tid * 8]);
            gload_lds16(vb_base + arow_off[1] + kofs, &Abuf[nxt][4096 + tid * 8]);
        }
        __builtin_amdgcn_s_setprio(1);
#pragma unroll
        for (int mi = 0; mi < 4; ++mi)
#pragma unroll
            for (int nj = 0; nj < 4; ++nj)
                acc[mi][nj] = __builtin_amdgcn_mfma_f32_16x16x32_bf16(aR[mi], bR[nj], acc[mi][nj], 0, 0, 0);
        __builtin_amdgcn_s_setprio(0);

        // ====== P1: pre-issue reads (A mi4-7 kk0) + stage A23; barrier; MFMA ======
#pragma unroll
        for (int mi = 0; mi < 4; ++mi) aR[mi] = *(const bf16x8*)&Ac[(arow + 64 + mi * 16) * 64 + kix0];
        if (t < 15) {
            gload_lds16(vb_base + arow_off[2] + kofs, &Abuf[nxt][2 * 4096 + tid * 8]);
            gload_lds16(vb_base + arow_off[3] + kofs, &Abuf[nxt][3 * 4096 + tid * 8]);
        }
        __builtin_amdgcn_sched_barrier(0);
        __builtin_amdgcn_s_barrier();
        __builtin_amdgcn_s_setprio(1);
#pragma unroll
        for (int mi = 0; mi < 4; ++mi)
#pragma unroll
            for (int nj = 0; nj < 4; ++nj)
                acc[mi + 4][nj] = __builtin_amdgcn_mfma_f32_16x16x32_bf16(aR[mi], bR[nj], acc[mi + 4][nj], 0, 0, 0);
        __builtin_amdgcn_s_setprio(0);

        // ====== P2: pre-issue reads (kk1, A mi0-3 + B) + stage B01; barrier; MFMA ======
#pragma unroll
        for (int mi = 0; mi < 4; ++mi) aR[mi] = *(const bf16x8*)&Ac[(arow + mi * 16) * 64 + kix1];
#pragma unroll
        for (int nj = 0; nj < 4; ++nj) bR[nj] = *(const bf16x8*)&Bc[(brow + nj * 16) * 64 + kix1];
        if (t < 15) {
            gload_lds16(bsrc + kofs,                   &Bbuf[nxt][tid * 8]);
            gload_lds16(bsrc + kofs + (size_t)65536,   &Bbuf[nxt][4096 + tid * 8]);
        }
        __builtin_amdgcn_sched_barrier(0);
        __builtin_amdgcn_s_barrier();
        __builtin_amdgcn_s_setprio(1);
#pragma unroll
        for (int mi = 0; mi < 4; ++mi)
#pragma unroll
            for (int nj = 0; nj < 4; ++nj)
                acc[mi][nj] = __builtin_amdgcn_mfma_f32_16x16x32_bf16(aR[mi], bR[nj], acc[mi][nj], 0, 0, 0);
        __builtin_amdgcn_s_setprio(0);

        // ====== P3: pre-issue reads (A mi4-7 kk1) + stage B23; barrier; MFMA ======
#pragma unroll
        for (int mi = 0; mi < 4; ++mi) aR[mi] = *(const bf16x8*)&Ac[(arow + 64 + mi * 16) * 64 + kix1];
        if (t < 15) {
            gload_lds16(bsrc + kofs + (size_t)2 * 65536, &Bbuf[nxt][2 * 4096 + tid * 8]);
            gload_lds16(bsrc + kofs + (size_t)3 * 65536, &Bbuf[nxt][3 * 4096 + tid * 8]);
        }
        __builtin_amdgcn_sched_barrier(0);
        __builtin_amdgcn_s_barrier();
        __builtin_amdgcn_s_setprio(1);
#pragma unroll
        for (int mi = 0; mi < 4; ++mi)
#pragma unroll
            for (int nj = 0; nj < 4; ++nj)
                acc[mi + 4][nj] = __builtin_amdgcn_mfma_f32_16x16x32_bf16(aR[mi], bR[nj], acc[mi + 4][nj], 0, 0, 0);
        __builtin_amdgcn_s_setprio(0);
        // loop-top pub barrier closes the tile
    }

    // ---- fused epilogue: tanh(x + qpb)*v, reduce cols, scatter to original rows ----
    float rs[8][4];
#pragma unroll
    for (int mi = 0; mi < 8; ++mi)
#pragma unroll
        for (int r = 0; r < 4; ++r) rs[mi][r] = 0.f;

#pragma unroll
    for (int nj = 0; nj < 4; ++nj) {
        const int cl = wn * 64 + nj * 16 + colL;
        const float qadd = qv_lds[cl];
        const float vmul = vv_lds[cl];
#pragma unroll
        for (int mi = 0; mi < 8; ++mi)
#pragma unroll
            for (int r = 0; r < 4; ++r)
                rs[mi][r] += fast_tanh(acc[mi][nj][r] + qadd) * vmul;
    }
#pragma unroll
    for (int mi = 0; mi < 8; ++mi)
#pragma unroll
        for (int r = 0; r < 4; ++r) {
            float s = rs[mi][r];
            s += __shfl_xor(s, 1); s += __shfl_xor(s, 2);
            s += __shfl_xor(s, 4); s += __shfl_xor(s, 8);
            if (colL == 0) red[wn][wm * 128 + mi * 16 + grp * 4 + r] = s;
        }
    __syncthreads();
    if (tid < 256) {
        const int cp = lm * 256 + tid;
        if (cp < cnt_b) {
            const int orig = ib[cp];
            spart[(size_t)nt * M_TOT + bb * S_DIM + orig] =
                red[0][tid] + red[1][tid] + red[2][tid] + red[3][tid];
        }
    }
}

// ---------- fallback score kernel (fp32, no MFMA) ----------
__global__ __launch_bounds__(256)
void score_fallback_kernel(const float* __restrict__ values, const float* __restrict__ w2,
                           const float* __restrict__ qpb, const float* __restrict__ vvec,
                           float* __restrict__ spart) {
    int row0 = blockIdx.x * 16;
    int b = row0 >> 11;
    __shared__ float vr[16][D_DIM];
    for (int i = threadIdx.x; i < 16 * D_DIM; i += 256)
        vr[i >> 10][i & 1023] = values[(size_t)row0 * D_DIM + i];
    __syncthreads();
    float rs[16];
#pragma unroll
    for (int r = 0; r < 16; ++r) rs[r] = 0.f;
    for (int uu = threadIdx.x; uu < U_DIM; uu += 256) {
        float acc[16];
#pragma unroll
        for (int r = 0; r < 16; ++r) acc[r] = 0.f;
        for (int d = 0; d < D_DIM; ++d) {
            float wv = w2[(size_t)d * U_DIM + uu];
#pragma unroll
            for (int r = 0; r < 16; ++r) acc[r] += vr[r][d] * wv;
        }
        float qv = qpb[b * U_DIM + uu], vu = vvec[uu];
#pragma unroll
        for (int r = 0; r < 16; ++r) rs[r] += fast_tanh(acc[r] + qv) * vu;
    }
#pragma unroll
    for (int r = 0; r < 16; ++r) {
        float s = rs[r];
        for (int o = 1; o < 64; o <<= 1) s += __shfl_xor(s, o);
        rs[r] = s;
    }
    __shared__ float wred[16][4];
    int lane = threadIdx.x & 63, wid = threadIdx.x >> 6;
    if (lane == 0)
        for (int r = 0; r < 16; ++r) wred[r][wid] = rs[r];
    __syncthreads();
    if (threadIdx.x < 16)
        spart[row0 + threadIdx.x] = wred[threadIdx.x][0] + wred[threadIdx.x][1] +
                                    wred[threadIdx.x][2] + wred[threadIdx.x][3];
}

// ---------- kernel 3: masked softmax over S per batch ----------
__global__ void softmax_kernel(const float* __restrict__ spart, const int* __restrict__ mask,
                               float* __restrict__ wout, int nparts) {
    int b = blockIdx.x, t = threadIdx.x;
    float sc[8]; int mk[8];
    float mx = -1e30f;
#pragma unroll
    for (int i = 0; i < 8; ++i) {
        int s = t + i * 256;
        mk[i] = mask[b * S_DIM + s];
        float vsum = 0.f;
        if (mk[i])
            for (int p = 0; p < nparts; ++p) vsum += spart[(size_t)p * M_TOT + b * S_DIM + s];
        sc[i] = vsum;
        if (mk[i]) mx = fmaxf(mx, vsum);
    }
    for (int o = 1; o < 64; o <<= 1) mx = fmaxf(mx, __shfl_xor(mx, o));
    __shared__ float red[4], red2[4];
    if ((t & 63) == 0) red[t >> 6] = mx;
    __syncthreads();
    mx = fmaxf(fmaxf(red[0], red[1]), fmaxf(red[2], red[3]));
    float sum = 0.f, ev[8];
#pragma unroll
    for (int i = 0; i < 8; ++i) {
        ev[i] = mk[i] ? __expf(sc[i] - mx) : 0.f;
        sum += ev[i];
    }
    for (int o = 1; o < 64; o <<= 1) sum += __shfl_xor(sum, o);
    if ((t & 63) == 0) red2[t >> 6] = sum;
    __syncthreads();
    sum = red2[0] + red2[1] + red2[2] + red2[3];
    float inv = 1.0f / sum;
#pragma unroll
    for (int i = 0; i < 8; ++i) wout[b * S_DIM + t + i * 256] = ev[i] * inv;
}

// ---------- kernel 4: context partials, grid-stride over UNMASKED rows ----------
// grid (32, 32), 128 threads: block (b,c) strides compacted rows c, c+32, ...
__global__ void ctx_partial_kernel(const u16* __restrict__ vbf, const float* __restrict__ w,
                                   const int* __restrict__ idx, const int* __restrict__ cnt,
                                   float* __restrict__ part) {
    const int b = blockIdx.x, c = blockIdx.y, t = threadIdx.x;
    const int cb = cnt[b];
    const int* ib = idx + b * S_DIM;
    const u16* vb0 = vbf + (size_t)b * S_DIM * D_DIM + t * 8;
    float acc[8];
#pragma unroll
    for (int i = 0; i < 8; ++i) acc[i] = 0.f;
    for (int ii = c; ii < cb; ii += 32) {
        const int s = ib[ii];
        const float wv = w[b * S_DIM + s];
        u16x8 vv = *(const u16x8*)(vb0 + (size_t)s * D_DIM);
#pragma unroll
        for (int i = 0; i < 8; ++i) acc[i] += wv * bf2f(vv[i]);
    }
    float* pp = part + ((size_t)b * 32 + c) * D_DIM + t * 8;
#pragma unroll
    for (int i = 0; i < 8; ++i) pp[i] = acc[i];
}
// fp32 variant for fallback path
__global__ void ctx_partial_f32_kernel(const float* __restrict__ values, const float* __restrict__ w,
                                       float* __restrict__ part) {
    int b = blockIdx.x, c = blockIdx.y, t = threadIdx.x;
    const float4* vb = (const float4*)(values + ((size_t)b * S_DIM + c * 256) * D_DIM) + t;
    const float* wb = w + b * S_DIM + c * 256;
    float a0 = 0, a1 = 0, a2 = 0, a3 = 0;
    for (int s = 0; s < 256; ++s) {
        float wv = wb[s];
        float4 vv = vb[(size_t)s * 256];
        a0 += wv * vv.x; a1 += wv * vv.y; a2 += wv * vv.z; a3 += wv * vv.w;
    }
    float* pp = part + ((size_t)b * 8 + c) * D_DIM + t * 4;
    pp[0] = a0; pp[1] = a1; pp[2] = a2; pp[3] = a3;
}

// ---------- kernel 5: reduce context partials ----------
__global__ void ctx_reduce_kernel(const float* __restrict__ part, float* __restrict__ out, int nchunks) {
    int b = blockIdx.x, t = threadIdx.x;
    for (int d = t; d < D_DIM; d += 256) {
        float s = 0.f;
        for (int c = 0; c < nchunks; ++c) s += part[((size_t)b * nchunks + c) * D_DIM + d];
        out[b * D_DIM + d] = s;
    }
}

extern "C" void kernel_launch(void* const* d_in, const int* in_sizes, int n_in,
                              void* d_out, int out_size, void* d_ws, size_t ws_size,
                              hipStream_t stream) {
    const float* query  = (const float*)d_in[0];
    const float* values = (const float*)d_in[1];
    const int*   mask   = (const int*)d_in[2];
    const float* w1     = (const float*)d_in[3];
    const float* b1     = (const float*)d_in[4];
    const float* w2     = (const float*)d_in[5];
    const float* b2     = (const float*)d_in[6];
    const float* v      = (const float*)d_in[7];
    // bv (d_in[8]) shifts all scores equally -> softmax-invariant -> unused.

    float* out  = (float*)d_out;              // context [32][1024]
    float* wout = out + B_DIM * D_DIM;        // attention weights [32][2048]
    char* ws = (char*)d_ws;

    const size_t SZ_VBF = (size_t)M_TOT * D_DIM * 2;    // 134 MB bf16 values
    const size_t SZ_W2T = (size_t)U_DIM * D_DIM * 2;    // 2 MB
    const size_t SZ_QPB = (size_t)B_DIM * U_DIM * 4;    // 128 KB
    const size_t SZ_SPART = (size_t)8 * M_TOT * 4;      // 2 MB (4 used)
    const size_t SZ_PART  = (size_t)B_DIM * 32 * D_DIM * 4; // 4 MB
    const size_t SZ_IDX   = (size_t)M_TOT * 4 + 4096;   // idx + cnt
    const size_t need = SZ_VBF + SZ_W2T + SZ_QPB + SZ_SPART + SZ_PART + SZ_IDX;

    if (ws_size >= need) {
        u16*   vbf   = (u16*)ws;
        u16*   w2t   = (u16*)(ws + SZ_VBF);
        float* qpb   = (float*)(ws + SZ_VBF + SZ_W2T);
        float* spart = (float*)(ws + SZ_VBF + SZ_W2T + SZ_QPB);
        float* part  = (float*)(ws + SZ_VBF + SZ_W2T + SZ_QPB + SZ_SPART);
        int*   idx   = (int*)(ws + SZ_VBF + SZ_W2T + SZ_QPB + SZ_SPART + SZ_PART);
        int*   cnt   = idx + M_TOT;

        build_index_kernel<<<32, 256, 0, stream>>>(mask, idx, cnt);
        convert_masked_kernel<<<dim3(32, 64), 256, 0, stream>>>(values, vbf, idx, cnt);
        transpose_w2_kernel<<<dim3(32, 32), dim3(32, 8), 0, stream>>>(w2, w2t);
        qproj_kernel<<<dim3(32, 32), 256, 0, stream>>>(query, w1, b1, b2, qpb);
        score_gemm8_kernel<<<1024, 512, 0, stream>>>(vbf, w2t, qpb, v, idx, cnt, spart);
        softmax_kernel<<<32, 256, 0, stream>>>(spart, mask, wout, 4);
        ctx_partial_kernel<<<dim3(32, 32), 128, 0, stream>>>(vbf, wout, idx, cnt, part);
        ctx_reduce_kernel<<<32, 256, 0, stream>>>(part, out, 32);
    } else {
        // conservative fp32 fallback (no big scratch available)
        float* qpb   = (float*)ws;
        float* spart = (float*)(ws + SZ_QPB);
        float* part  = (float*)(ws + SZ_QPB + (size_t)M_TOT * 4);
        qproj_kernel<<<dim3(32, 32), 256, 0, stream>>>(query, w1, b1, b2, qpb);
        score_fallback_kernel<<<4096, 256, 0, stream>>>(values, w2, qpb, v, spart);
        softmax_kernel<<<32, 256, 0, stream>>>(spart, mask, wout, 1);
        ctx_partial_f32_kernel<<<dim3(32, 8), 256, 0, stream>>>(values, wout, part);
        ctx_reduce_kernel<<<32, 256, 0, stream>>>(part, out, 8);
    }
}

// Round 14
// 217.503 us; speedup vs baseline: 1.4930x; 1.0460x over previous
//
#include <hip/hip_runtime.h>
#include <cstdint>

typedef unsigned short u16;
typedef __bf16 bf16x8 __attribute__((ext_vector_type(8)));
typedef float f32x4 __attribute__((ext_vector_type(4)));
typedef u16 u16x8 __attribute__((ext_vector_type(8)));

#define B_DIM 32
#define S_DIM 2048
#define D_DIM 1024
#define U_DIM 1024
#define M_TOT (B_DIM * S_DIM)   // 65536 rows

// ---------- helpers ----------
__device__ __forceinline__ u16 f2bf(float f) {
    union { float f; uint32_t u; } a; a.f = f;
    uint32_t u = a.u;
    uint32_t r = (u + 0x7FFFu + ((u >> 16) & 1u)) >> 16;   // RNE
    return (u16)r;
}
__device__ __forceinline__ float bf2f(u16 h) {
    union { uint32_t u; float f; } a; a.u = ((uint32_t)h) << 16;
    return a.f;
}
__device__ __forceinline__ float fast_tanh(float x) {
    float ax = fabsf(x);
    float e  = __expf(-2.0f * ax);
    float th = __fdividef(1.0f - e, 1.0f + e);
    return copysignf(th, x);
}
// global -> LDS async copy, 16B per lane
__device__ __forceinline__ void gload_lds16(const void* g, void* l) {
    __builtin_amdgcn_global_load_lds(
        (__attribute__((address_space(1))) void*)(uintptr_t)g,
        (__attribute__((address_space(3))) void*)(uint32_t)(uintptr_t)l,
        16, 0, 0);
}

// ---------- kernel P: fused prep (build_index | qproj | transpose_w2) ----------
// grid 2080: [0,32) build_index; [32,1056) qproj (b,uc); [1056,2080) transpose (bx,by)
__global__ void prep_kernel(const int* __restrict__ mask, int* __restrict__ idx, int* __restrict__ cnt,
                            const float* __restrict__ q, const float* __restrict__ w1,
                            const float* __restrict__ b1, const float* __restrict__ b2,
                            float* __restrict__ qpb,
                            const float* __restrict__ w2, u16* __restrict__ w2t) {
    const int bid = blockIdx.x;
    const int t = threadIdx.x;
    if (bid < 32) {
        // ---- per-batch compaction ----
        const int b = bid;
        __shared__ int wsum[4];
        const int base = t * 8;
        int m[8]; int c = 0;
#pragma unroll
        for (int i = 0; i < 8; ++i) { m[i] = mask[b * S_DIM + base + i] != 0; c += m[i]; }
        const int lane = t & 63, w = t >> 6;
        int pre = c;
        for (int o = 1; o < 64; o <<= 1) { int v = __shfl_up(pre, o); if (lane >= o) pre += v; }
        if (lane == 63) wsum[w] = pre;
        __syncthreads();
        int woff = 0;
        for (int i = 0; i < w; ++i) woff += wsum[i];
        int excl = woff + pre - c;
#pragma unroll
        for (int i = 0; i < 8; ++i) if (m[i]) idx[b * S_DIM + excl++] = base + i;
        if (t == 255) cnt[b] = woff + pre;
    } else if (bid < 1056) {
        // ---- qproj: block (b, uc) computes u in [uc*32, +32) ----
        const int qb = bid - 32;
        const int b = qb >> 5, uc = qb & 31;
        const int u0 = uc * 32;
        const int ul = t & 31;
        const int dg = t >> 5;   // 0..7
        __shared__ float ql[D_DIM];
        __shared__ float redq[8][32];
        for (int d = t; d < D_DIM; d += 256) ql[d] = q[b * D_DIM + d];
        __syncthreads();
        float acc = 0.f;
        const int d0 = dg * 128;
        for (int d = d0; d < d0 + 128; ++d)
            acc += ql[d] * w1[(size_t)d * U_DIM + u0 + ul];
        redq[dg][ul] = acc;
        __syncthreads();
        if (t < 32) {
            float s = b1[u0 + ul] + b2[u0 + ul];
#pragma unroll
            for (int g = 0; g < 8; ++g) s += redq[g][ul];
            qpb[b * U_DIM + u0 + ul] = s;
        }
    } else {
        // ---- transpose w2 [D][U] -> w2t [U][D] bf16 ----
        const int tq = bid - 1056;
        const int bx = (tq >> 5) * 32, by = (tq & 31) * 32;
        const int tx = t & 31, ty = t >> 5;  // ty 0..7
        __shared__ float tile[32][33];
        for (int i = 0; i < 32; i += 8)
            tile[ty + i][tx] = w2[(size_t)(by + ty + i) * U_DIM + bx + tx];
        __syncthreads();
        for (int i = 0; i < 32; i += 8)
            w2t[(size_t)(bx + ty + i) * D_DIM + by + tx] = f2bf(tile[tx][ty + i]);
    }
}

// ---------- kernel 1a: values f32 -> bf16, UNMASKED rows only ----------
__global__ void convert_masked_kernel(const float* __restrict__ values, u16* __restrict__ vbf,
                                      const int* __restrict__ idx, const int* __restrict__ cnt) {
    const int b = blockIdx.x, c = blockIdx.y, t = threadIdx.x;
    const int cb = cnt[b];
    const int* ib = idx + b * S_DIM;
    for (int ii = c; ii < cb; ii += 64) {
        const int s = ib[ii];
        const float4* src = (const float4*)(values + ((size_t)b * S_DIM + s) * D_DIM) + t;
        ushort4* dst = (ushort4*)(vbf + ((size_t)b * S_DIM + s) * D_DIM) + t;
        float4 v = *src;
        ushort4 o;
        o.x = f2bf(v.x); o.y = f2bf(v.y); o.z = f2bf(v.z); o.w = f2bf(v.w);
        *dst = o;
    }
}

// ---------- kernel 2: compacted-row 128x128-tile, 4-wave GEMM (2 blocks/CU) ----------
// m97-proven geometry: 64 KB LDS dbuf -> 2 independent blocks/CU provide the
// DS-pipe / MFMA-pipe overlap the 8-wave lockstep block couldn't.
// Race-safe schedule (round 11): all staging issued AFTER the pub barrier;
// one vmcnt(0)+barrier per K-tile. Proven 64-col XOR swizzle unchanged.
__global__ __launch_bounds__(256, 2)
void score_gemm4_kernel(const u16* __restrict__ vbf, const u16* __restrict__ w2t,
                        const float* __restrict__ qpb, const float* __restrict__ vvec,
                        const int* __restrict__ idx, const int* __restrict__ cnt,
                        float* __restrict__ spart) {
    const int p    = blockIdx.x;             // 0..4095
    const int xcd  = p & 7;
    const int slot = p >> 3;
    const int g    = xcd * 512 + slot;       // batch-grouped per XCD (A+B ~4MB ~ L2)
    const int bb   = g >> 7;                 // batch
    const int rem  = g & 127;
    const int lm   = rem >> 3;               // 0..15 (compacted m-tile of 128)
    const int nt   = rem & 7;                // 0..7
    const int n0   = nt * 128;

    const int cnt_b = cnt[bb];
    if (lm * 128 >= cnt_b) return;           // uniform exit, before any barrier

    __shared__ __align__(16) __bf16 Abuf[2][128 * 64];   // 32 KB
    __shared__ __align__(16) __bf16 Bbuf[2][128 * 64];   // 32 KB
    __shared__ float qv_lds[128], vv_lds[128];
    __shared__ float red[2][128];

    const int tid  = threadIdx.x;
    const int lane = tid & 63;
    const int wid  = tid >> 6;     // 0..3
    const int wm   = wid >> 1;     // 0..1
    const int wn   = wid & 1;      // 0..1

    if (tid < 128) qv_lds[tid] = qpb[bb * U_DIM + n0 + tid];
    else           vv_lds[tid - 128] = vvec[n0 + (tid - 128)];

    // staging: issue j covers rows [j*32, +32); thread row tr = tid>>3
    const int tr = tid >> 3;                              // 0..31
    const int sc = (((tid & 7) ^ (tr & 7)) << 3);         // swizzled source col (elems)
    const int* ib = idx + bb * S_DIM;
    const u16* vb_base = vbf + (size_t)bb * S_DIM * D_DIM + sc;
    size_t arow_off[4];
#pragma unroll
    for (int j = 0; j < 4; ++j) {
        int cp = lm * 128 + tr + j * 32;
        cp = cp < cnt_b ? cp : cnt_b - 1;                 // clamp: dup of last valid row
        arow_off[j] = (size_t)ib[cp] * D_DIM;
    }
    const u16* bsrc = w2t + (size_t)(n0 + tr) * D_DIM + sc;

    // prologue: stage K-tile 0 into buffer 0
#pragma unroll
    for (int j = 0; j < 4; ++j) {
        gload_lds16(vb_base + arow_off[j], &Abuf[0][j * 2048 + tid * 8]);
        gload_lds16(bsrc + (size_t)j * 32 * D_DIM, &Bbuf[0][j * 2048 + tid * 8]);
    }

    f32x4 acc[4][4];
#pragma unroll
    for (int mi = 0; mi < 4; ++mi)
#pragma unroll
        for (int nj = 0; nj < 4; ++nj) acc[mi][nj] = (f32x4){0.f, 0.f, 0.f, 0.f};

    const int colL = lane & 15;
    const int grp  = lane >> 4;
    const int xork = (lane & 7) << 3;
    const int kix0 = (grp * 8) ^ xork;        // kk=0 swizzled col
    const int kix1 = ((32 + grp * 8)) ^ xork; // kk=1 swizzled col
    const int arow = wm * 64 + colL;
    const int brow = wn * 64 + colL;

    bf16x8 aR[4], bR[4];

    for (int t = 0; t < 16; ++t) {
        const int cur = t & 1, nxt = cur ^ 1;
        const __bf16* Ac = Abuf[cur];
        const __bf16* Bc = Bbuf[cur];
        const size_t kofs = (size_t)(t + 1) * 64;

        // ---- publish tile t: only tile t's 8 loads are outstanding ----
        asm volatile("s_waitcnt vmcnt(0)" ::: "memory");
        __builtin_amdgcn_s_barrier();
        __builtin_amdgcn_sched_barrier(0);

        // ---- kk0: frag reads; stage ALL of t+1 (after pub barrier -> race-safe); MFMA
#pragma unroll
        for (int mi = 0; mi < 4; ++mi) aR[mi] = *(const bf16x8*)&Ac[(arow + mi * 16) * 64 + kix0];
#pragma unroll
        for (int nj = 0; nj < 4; ++nj) bR[nj] = *(const bf16x8*)&Bc[(brow + nj * 16) * 64 + kix0];
        if (t < 15) {
#pragma unroll
            for (int j = 0; j < 4; ++j) {
                gload_lds16(vb_base + arow_off[j] + kofs, &Abuf[nxt][j * 2048 + tid * 8]);
                gload_lds16(bsrc + kofs + (size_t)j * 32 * D_DIM, &Bbuf[nxt][j * 2048 + tid * 8]);
            }
        }
        __builtin_amdgcn_s_setprio(1);
#pragma unroll
        for (int mi = 0; mi < 4; ++mi)
#pragma unroll
            for (int nj = 0; nj < 4; ++nj)
                acc[mi][nj] = __builtin_amdgcn_mfma_f32_16x16x32_bf16(aR[mi], bR[nj], acc[mi][nj], 0, 0, 0);
        __builtin_amdgcn_s_setprio(0);

        // ---- kk1: frag reads; MFMA ----
#pragma unroll
        for (int mi = 0; mi < 4; ++mi) aR[mi] = *(const bf16x8*)&Ac[(arow + mi * 16) * 64 + kix1];
#pragma unroll
        for (int nj = 0; nj < 4; ++nj) bR[nj] = *(const bf16x8*)&Bc[(brow + nj * 16) * 64 + kix1];
        __builtin_amdgcn_s_setprio(1);
#pragma unroll
        for (int mi = 0; mi < 4; ++mi)
#pragma unroll
            for (int nj = 0; nj < 4; ++nj)
                acc[mi][nj] = __builtin_amdgcn_mfma_f32_16x16x32_bf16(aR[mi], bR[nj], acc[mi][nj], 0, 0, 0);
        __builtin_amdgcn_s_setprio(0);
    }

    // ---- fused epilogue: tanh(x + qpb)*v, reduce cols, scatter to original rows ----
    float rs[4][4];
#pragma unroll
    for (int mi = 0; mi < 4; ++mi)
#pragma unroll
        for (int r = 0; r < 4; ++r) rs[mi][r] = 0.f;

#pragma unroll
    for (int nj = 0; nj < 4; ++nj) {
        const int cl = wn * 64 + nj * 16 + colL;
        const float qadd = qv_lds[cl];
        const float vmul = vv_lds[cl];
#pragma unroll
        for (int mi = 0; mi < 4; ++mi)
#pragma unroll
            for (int r = 0; r < 4; ++r)
                rs[mi][r] += fast_tanh(acc[mi][nj][r] + qadd) * vmul;
    }
#pragma unroll
    for (int mi = 0; mi < 4; ++mi)
#pragma unroll
        for (int r = 0; r < 4; ++r) {
            float s = rs[mi][r];
            s += __shfl_xor(s, 1); s += __shfl_xor(s, 2);
            s += __shfl_xor(s, 4); s += __shfl_xor(s, 8);
            if (colL == 0) red[wn][wm * 64 + mi * 16 + grp * 4 + r] = s;
        }
    __syncthreads();
    if (tid < 128) {
        const int cp = lm * 128 + tid;
        if (cp < cnt_b) {
            const int orig = ib[cp];
            spart[(size_t)nt * M_TOT + bb * S_DIM + orig] = red[0][tid] + red[1][tid];
        }
    }
}

// ---------- standalone qproj (fallback path only) ----------
__global__ void qproj_kernel(const float* __restrict__ q, const float* __restrict__ w1,
                             const float* __restrict__ b1, const float* __restrict__ b2,
                             float* __restrict__ qpb) {
    const int b = blockIdx.x, uc = blockIdx.y;
    const int u0 = uc * 32;
    const int ul = threadIdx.x & 31;
    const int dg = threadIdx.x >> 5;
    __shared__ float ql[D_DIM];
    __shared__ float redq[8][32];
    for (int d = threadIdx.x; d < D_DIM; d += 256) ql[d] = q[b * D_DIM + d];
    __syncthreads();
    float acc = 0.f;
    const int d0 = dg * 128;
    for (int d = d0; d < d0 + 128; ++d)
        acc += ql[d] * w1[(size_t)d * U_DIM + u0 + ul];
    redq[dg][ul] = acc;
    __syncthreads();
    if (threadIdx.x < 32) {
        float s = b1[u0 + ul] + b2[u0 + ul];
#pragma unroll
        for (int g = 0; g < 8; ++g) s += redq[g][ul];
        qpb[b * U_DIM + u0 + ul] = s;
    }
}

// ---------- fallback score kernel (fp32, no MFMA) ----------
__global__ __launch_bounds__(256)
void score_fallback_kernel(const float* __restrict__ values, const float* __restrict__ w2,
                           const float* __restrict__ qpb, const float* __restrict__ vvec,
                           float* __restrict__ spart) {
    int row0 = blockIdx.x * 16;
    int b = row0 >> 11;
    __shared__ float vr[16][D_DIM];
    for (int i = threadIdx.x; i < 16 * D_DIM; i += 256)
        vr[i >> 10][i & 1023] = values[(size_t)row0 * D_DIM + i];
    __syncthreads();
    float rs[16];
#pragma unroll
    for (int r = 0; r < 16; ++r) rs[r] = 0.f;
    for (int uu = threadIdx.x; uu < U_DIM; uu += 256) {
        float acc[16];
#pragma unroll
        for (int r = 0; r < 16; ++r) acc[r] = 0.f;
        for (int d = 0; d < D_DIM; ++d) {
            float wv = w2[(size_t)d * U_DIM + uu];
#pragma unroll
            for (int r = 0; r < 16; ++r) acc[r] += vr[r][d] * wv;
        }
        float qv = qpb[b * U_DIM + uu], vu = vvec[uu];
#pragma unroll
        for (int r = 0; r < 16; ++r) rs[r] += fast_tanh(acc[r] + qv) * vu;
    }
#pragma unroll
    for (int r = 0; r < 16; ++r) {
        float s = rs[r];
        for (int o = 1; o < 64; o <<= 1) s += __shfl_xor(s, o);
        rs[r] = s;
    }
    __shared__ float wred[16][4];
    int lane = threadIdx.x & 63, wid = threadIdx.x >> 6;
    if (lane == 0)
        for (int r = 0; r < 16; ++r) wred[r][wid] = rs[r];
    __syncthreads();
    if (threadIdx.x < 16)
        spart[row0 + threadIdx.x] = wred[threadIdx.x][0] + wred[threadIdx.x][1] +
                                    wred[threadIdx.x][2] + wred[threadIdx.x][3];
}

// ---------- kernel 3: masked softmax over S per batch ----------
__global__ void softmax_kernel(const float* __restrict__ spart, const int* __restrict__ mask,
                               float* __restrict__ wout, int nparts) {
    int b = blockIdx.x, t = threadIdx.x;
    float sc[8]; int mk[8];
    float mx = -1e30f;
#pragma unroll
    for (int i = 0; i < 8; ++i) {
        int s = t + i * 256;
        mk[i] = mask[b * S_DIM + s];
        float vsum = 0.f;
        if (mk[i])
            for (int p = 0; p < nparts; ++p) vsum += spart[(size_t)p * M_TOT + b * S_DIM + s];
        sc[i] = vsum;
        if (mk[i]) mx = fmaxf(mx, vsum);
    }
    for (int o = 1; o < 64; o <<= 1) mx = fmaxf(mx, __shfl_xor(mx, o));
    __shared__ float red[4], red2[4];
    if ((t & 63) == 0) red[t >> 6] = mx;
    __syncthreads();
    mx = fmaxf(fmaxf(red[0], red[1]), fmaxf(red[2], red[3]));
    float sum = 0.f, ev[8];
#pragma unroll
    for (int i = 0; i < 8; ++i) {
        ev[i] = mk[i] ? __expf(sc[i] - mx) : 0.f;
        sum += ev[i];
    }
    for (int o = 1; o < 64; o <<= 1) sum += __shfl_xor(sum, o);
    if ((t & 63) == 0) red2[t >> 6] = sum;
    __syncthreads();
    sum = red2[0] + red2[1] + red2[2] + red2[3];
    float inv = 1.0f / sum;
#pragma unroll
    for (int i = 0; i < 8; ++i) wout[b * S_DIM + t + i * 256] = ev[i] * inv;
}

// ---------- kernel 4: context partials, grid-stride over UNMASKED rows ----------
__global__ void ctx_partial_kernel(const u16* __restrict__ vbf, const float* __restrict__ w,
                                   const int* __restrict__ idx, const int* __restrict__ cnt,
                                   float* __restrict__ part) {
    const int b = blockIdx.x, c = blockIdx.y, t = threadIdx.x;
    const int cb = cnt[b];
    const int* ib = idx + b * S_DIM;
    const u16* vb0 = vbf + (size_t)b * S_DIM * D_DIM + t * 8;
    float acc[8];
#pragma unroll
    for (int i = 0; i < 8; ++i) acc[i] = 0.f;
    for (int ii = c; ii < cb; ii += 32) {
        const int s = ib[ii];
        const float wv = w[b * S_DIM + s];
        u16x8 vv = *(const u16x8*)(vb0 + (size_t)s * D_DIM);
#pragma unroll
        for (int i = 0; i < 8; ++i) acc[i] += wv * bf2f(vv[i]);
    }
    float* pp = part + ((size_t)b * 32 + c) * D_DIM + t * 8;
#pragma unroll
    for (int i = 0; i < 8; ++i) pp[i] = acc[i];
}
// fp32 variant for fallback path
__global__ void ctx_partial_f32_kernel(const float* __restrict__ values, const float* __restrict__ w,
                                       float* __restrict__ part) {
    int b = blockIdx.x, c = blockIdx.y, t = threadIdx.x;
    const float4* vb = (const float4*)(values + ((size_t)b * S_DIM + c * 256) * D_DIM) + t;
    const float* wb = w + b * S_DIM + c * 256;
    float a0 = 0, a1 = 0, a2 = 0, a3 = 0;
    for (int s = 0; s < 256; ++s) {
        float wv = wb[s];
        float4 vv = vb[(size_t)s * 256];
        a0 += wv * vv.x; a1 += wv * vv.y; a2 += wv * vv.z; a3 += wv * vv.w;
    }
    float* pp = part + ((size_t)b * 8 + c) * D_DIM + t * 4;
    pp[0] = a0; pp[1] = a1; pp[2] = a2; pp[3] = a3;
}

// ---------- kernel 5: reduce context partials ----------
__global__ void ctx_reduce_kernel(const float* __restrict__ part, float* __restrict__ out, int nchunks) {
    int b = blockIdx.x, t = threadIdx.x;
    for (int d = t; d < D_DIM; d += 256) {
        float s = 0.f;
        for (int c = 0; c < nchunks; ++c) s += part[((size_t)b * nchunks + c) * D_DIM + d];
        out[b * D_DIM + d] = s;
    }
}

extern "C" void kernel_launch(void* const* d_in, const int* in_sizes, int n_in,
                              void* d_out, int out_size, void* d_ws, size_t ws_size,
                              hipStream_t stream) {
    const float* query  = (const float*)d_in[0];
    const float* values = (const float*)d_in[1];
    const int*   mask   = (const int*)d_in[2];
    const float* w1     = (const float*)d_in[3];
    const float* b1     = (const float*)d_in[4];
    const float* w2     = (const float*)d_in[5];
    const float* b2     = (const float*)d_in[6];
    const float* v      = (const float*)d_in[7];
    // bv (d_in[8]) shifts all scores equally -> softmax-invariant -> unused.

    float* out  = (float*)d_out;              // context [32][1024]
    float* wout = out + B_DIM * D_DIM;        // attention weights [32][2048]
    char* ws = (char*)d_ws;

    const size_t SZ_VBF = (size_t)M_TOT * D_DIM * 2;    // 134 MB bf16 values
    const size_t SZ_W2T = (size_t)U_DIM * D_DIM * 2;    // 2 MB
    const size_t SZ_QPB = (size_t)B_DIM * U_DIM * 4;    // 128 KB
    const size_t SZ_SPART = (size_t)8 * M_TOT * 4;      // 2 MB (8 parts)
    const size_t SZ_PART  = (size_t)B_DIM * 32 * D_DIM * 4; // 4 MB
    const size_t SZ_IDX   = (size_t)M_TOT * 4 + 4096;   // idx + cnt
    const size_t need = SZ_VBF + SZ_W2T + SZ_QPB + SZ_SPART + SZ_PART + SZ_IDX;

    if (ws_size >= need) {
        u16*   vbf   = (u16*)ws;
        u16*   w2t   = (u16*)(ws + SZ_VBF);
        float* qpb   = (float*)(ws + SZ_VBF + SZ_W2T);
        float* spart = (float*)(ws + SZ_VBF + SZ_W2T + SZ_QPB);
        float* part  = (float*)(ws + SZ_VBF + SZ_W2T + SZ_QPB + SZ_SPART);
        int*   idx   = (int*)(ws + SZ_VBF + SZ_W2T + SZ_QPB + SZ_SPART + SZ_PART);
        int*   cnt   = idx + M_TOT;

        prep_kernel<<<2080, 256, 0, stream>>>(mask, idx, cnt, query, w1, b1, b2, qpb, w2, w2t);
        convert_masked_kernel<<<dim3(32, 64), 256, 0, stream>>>(values, vbf, idx, cnt);
        score_gemm4_kernel<<<4096, 256, 0, stream>>>(vbf, w2t, qpb, v, idx, cnt, spart);
        softmax_kernel<<<32, 256, 0, stream>>>(spart, mask, wout, 8);
        ctx_partial_kernel<<<dim3(32, 32), 128, 0, stream>>>(vbf, wout, idx, cnt, part);
        ctx_reduce_kernel<<<32, 256, 0, stream>>>(part, out, 32);
    } else {
        // conservative fp32 fallback (no big scratch available)
        float* qpb   = (float*)ws;
        float* spart = (float*)(ws + SZ_QPB);
        float* part  = (float*)(ws + SZ_QPB + (size_t)M_TOT * 4);
        qproj_kernel<<<dim3(32, 32), 256, 0, stream>>>(query, w1, b1, b2, qpb);
        score_fallback_kernel<<<4096, 256, 0, stream>>>(values, w2, qpb, v, spart);
        softmax_kernel<<<32, 256, 0, stream>>>(spart, mask, wout, 1);
        ctx_partial_f32_kernel<<<dim3(32, 8), 256, 0, stream>>>(values, wout, part);
        ctx_reduce_kernel<<<32, 256, 0, stream>>>(part, out, 8);
    }
}